// Round 1
// baseline (64438.898 us; speedup 1.0000x reference)
//
#include <hip/hip_runtime.h>

// =====================================================================
// LSTM autoencoder v7: weight reads restructured off the TCP miss path.
// - 4x4 thread tiles (4 samples x 4 gates/dcol), K split 16-way in-wave,
//   butterfly shfl reduce. Cuts per-thread weight reads 2.5x and removes
//   the 16-lane duplicate-address global loads entirely.
// - Weights pre-packed at P0 into exact LDS image ([row][68] floats,
//   gate-interleaved, 4-float pad), streamed per 128-row chunk via
//   coalesced reg-staged bulk copies, double-buffered; chunk0 loads
//   issued into regs BEFORE the group-barrier wait (prefetch under hop).
// - h staged transposed [k][b] with quad-XOR swizzle (<=2-way banks).
// - Barrier scheme / h-exchange / epochs identical to v6.
// Old v6 kernel retained as fallback for smaller workspaces.
// =====================================================================

#define Bsz 128
#define Tsz 128
#define Fsz 128
#define Dsz 512
#define ND  2048
#define NBLK 256
#define NTHR 1024

// ---- ws layout (float offsets) ----
#define OFF_HT0  1024
#define OFF_HT1  (OFF_HT0 + Dsz*Bsz)
#define OFF_HMT  (OFF_HT1 + Dsz*Bsz)
#define OFF_WEND (OFF_HMT + Dsz*Bsz)

// old packed layout (fallback kernel)
#define OFF_P_EW0   OFF_WEND
#define OFF_P_EU0   (OFF_P_EW0 + Fsz*ND)
#define OFF_P_WSUM  (OFF_P_EU0 + Dsz*ND)
#define OFF_P_WDECA (OFF_P_WSUM + Dsz*ND)
#define OFF_P_DW0   (OFF_P_WDECA + Dsz*ND)
#define OFF_P_DU0   (OFF_P_DW0 + Fsz*ND)
#define OFF_P_DW1   (OFF_P_DU0 + Dsz*ND)
#define OFF_P_DU1   (OFF_P_DW1 + Dsz*ND)
#define OFF_P_BF    (OFF_P_DU1 + Dsz*ND)
#define OFF_P_DWT   (OFF_P_BF + ND)
#define WS_PACKED_FLOATS (OFF_P_DWT + Dsz*Fsz)
#define OFF_F_WSUM  OFF_WEND
#define OFF_F_WDECA (OFF_F_WSUM + Dsz*ND)
#define OFF_F_BF    (OFF_F_WDECA + Dsz*ND)
#define OFF_F_DWT   (OFF_F_BF + ND)
#define WS_FALLBACK_FLOATS (OFF_F_DWT + Dsz*Fsz)

// new packed layout (v7): per-matrix [dblk 32][rows][68] LDS images
#define NWR 68
#define NSX 20
#define OFF_N_EW0   OFF_WEND                        // 32*128*68 = 278528
#define OFF_N_EU0   (OFF_N_EW0 + 32*128*NWR)        // 32*512*68 = 1114112
#define OFF_N_WSUM  (OFF_N_EU0 + 32*512*NWR)
#define OFF_N_WDECA (OFF_N_WSUM + 32*512*NWR)
#define OFF_N_DCAT  (OFF_N_WDECA + 32*512*NWR)      // 32*1024*68 = 2228224
#define OFF_N_BF    (OFF_N_DCAT + 32*1024*NWR)
#define OFF_N_DWT   (OFF_N_BF + ND)
#define WS_N_FLOATS (OFF_N_DWT + Dsz*Fsz)           // 6,114,304 floats = 24.5 MB

__device__ __forceinline__ float sigf(float x) {
    return 1.0f / (1.0f + __expf(-x));
}
__device__ __forceinline__ float ld_coh(const float* p) {
    return __hip_atomic_load((float*)p, __ATOMIC_RELAXED, __HIP_MEMORY_SCOPE_AGENT);
}
__device__ __forceinline__ void st_coh(float* p, float v) {
    __hip_atomic_store(p, v, __ATOMIC_RELAXED, __HIP_MEMORY_SCOPE_AGENT);
}

// ---- split group barrier (32 members) ----
__device__ __forceinline__ void arrive(unsigned* slot, unsigned ep) {
    __syncthreads();
    if (threadIdx.x == 0)
        __hip_atomic_store(slot, ep, __ATOMIC_RELEASE, __HIP_MEMORY_SCOPE_AGENT);
}
__device__ __forceinline__ void wait_grp(unsigned* gslots, unsigned ep) {
    if (threadIdx.x < 64) {
        for (;;) {
            unsigned v = (threadIdx.x < 32)
                ? __hip_atomic_load(&gslots[threadIdx.x], __ATOMIC_RELAXED,
                                    __HIP_MEMORY_SCOPE_AGENT)
                : ep;
            if (__all(v >= ep)) break;
            __builtin_amdgcn_s_sleep(1);
        }
    }
    __syncthreads();
}
__device__ __forceinline__ void gbar_all(unsigned* slots, int blkid, unsigned ep) {
    __syncthreads();
    if (threadIdx.x == 0) {
        __threadfence();
        __hip_atomic_store(&slots[blkid], ep, __ATOMIC_RELEASE,
                           __HIP_MEMORY_SCOPE_AGENT);
    }
    if (threadIdx.x < 64) {
        for (;;) {
            unsigned mn = ~0u;
            #pragma unroll
            for (int q = 0; q < 4; ++q) {
                unsigned v = __hip_atomic_load(&slots[threadIdx.x * 4 + q],
                                               __ATOMIC_RELAXED, __HIP_MEMORY_SCOPE_AGENT);
                mn = min(mn, v);
            }
            if (__all(mn >= ep)) break;
            __builtin_amdgcn_s_sleep(1);
        }
        if (threadIdx.x == 0) __threadfence();
    }
    __syncthreads();
}

// =====================================================================
// ======================  v7 kernel  ==================================
// =====================================================================

__device__ __forceinline__ int swz3(int k) { return (k ^ (k >> 3)) & 3; }

// h gather: HTsrc[r*128 + row0 + bb] -> XL2[(rbase+r)][bb] (swizzled quads)
__device__ __forceinline__ void stageHn(float* XL2, const float* HTsrc, int row0, int rbase) {
    #pragma unroll
    for (int ii = 0; ii < 8; ++ii) {
        const int i = (int)threadIdx.x + ii * NTHR;
        const int r = i >> 4, bb = i & 15;
        const int k = rbase + r;
        XL2[k * NSX + ((((bb >> 2) ^ swz3(k)) << 2) | (bb & 3))] =
            ld_coh(HTsrc + (size_t)r * Bsz + row0 + bb);
    }
}

__device__ __forceinline__ float4 ldx4(const float* XL2, int k, int qb) {
    return *(const float4*)(XL2 + k * NSX + ((qb ^ swz3(k)) << 2));
}

#define FMA16(A0,A1,A2,A3,x4,w4) \
    A0.x += x4.x*w4.x; A0.y += x4.x*w4.y; A0.z += x4.x*w4.z; A0.w += x4.x*w4.w; \
    A1.x += x4.y*w4.x; A1.y += x4.y*w4.y; A1.z += x4.y*w4.z; A1.w += x4.y*w4.w; \
    A2.x += x4.z*w4.x; A2.y += x4.z*w4.y; A2.z += x4.z*w4.z; A2.w += x4.z*w4.w; \
    A3.x += x4.w*w4.x; A3.y += x4.w*w4.y; A3.z += x4.w*w4.z; A3.w += x4.w*w4.w;

__device__ __forceinline__ void consume128(const float* __restrict__ WBs,
        const float* __restrict__ XL2, int k0, int kc, int qb, int wv,
        float4& A0, float4& A1, float4& A2, float4& A3)
{
    #pragma unroll
    for (int j = 0; j < 8; ++j) {
        const int l = j * 16 + kc;
        const float4 x4 = ldx4(XL2, k0 + l, qb);
        const float4 w4 = *(const float4*)(WBs + l * NWR + (wv << 2));
        FMA16(A0, A1, A2, A3, x4, w4)
    }
}

// load chunk c (128 rows x 68 = 2176 float4) straight into LDS buffer
__device__ __forceinline__ void wchunk_to(const float* wbase, int c, float* WBd, int tid) {
    const float4* G = (const float4*)wbase + c * 2176;
    float4 a = G[tid], b = G[1024 + tid], cc = a;
    if (tid < 128) cc = G[2048 + tid];
    float4* L = (float4*)WBd;
    L[tid] = a; L[1024 + tid] = b;
    if (tid < 128) L[2048 + tid] = cc;
}

// stream NC chunks of wbase through WBA/WBB; chunk0 already in buffer S0
template<int NC, int S0>
__device__ __forceinline__ void mat_stream(const float* wbase, float* WBA, float* WBB,
        int tid, const float* XL2, int kc, int qb, int wv,
        float4& A0, float4& A1, float4& A2, float4& A3)
{
    #pragma unroll
    for (int c = 0; c < NC; ++c) {
        const float* curb = ((c & 1) ^ S0) ? WBB : WBA;
        float4 ra, rb, rc;
        if (c < NC - 1) {
            const float4* G = (const float4*)wbase + (c + 1) * 2176;
            ra = G[tid]; rb = G[1024 + tid]; rc = ra;
            if (tid < 128) rc = G[2048 + tid];
        }
        consume128(curb, XL2, c * 128, kc, qb, wv, A0, A1, A2, A3);
        if (c < NC - 1) {
            float* nx = (((c + 1) & 1) ^ S0) ? WBB : WBA;
            float4* L = (float4*)nx;
            L[tid] = ra; L[1024 + tid] = rb;
            if (tid < 128) L[2048 + tid] = rc;
            __syncthreads();
        }
    }
}

// x-part (K=128): x read direct from global (4 sample rows), W from LDS chunk
__device__ __forceinline__ void xpart128(const float* xb, int xstr, const float* WBs,
        int kc, int wv, float4& A0, float4& A1, float4& A2, float4& A3)
{
    #pragma unroll
    for (int j = 0; j < 8; ++j) {
        const int k = j * 16 + kc;
        float4 x4;
        x4.x = xb[k]; x4.y = xb[xstr + k]; x4.z = xb[2 * xstr + k]; x4.w = xb[3 * xstr + k];
        const float4 w4 = *(const float4*)(WBs + k * NWR + (wv << 2));
        FMA16(A0, A1, A2, A3, x4, w4)
    }
}
// t=0 decoder slow paths (raw strided weights, one-time)
__device__ __forceinline__ void xpart_raw(const float* xb, int xstr, const float* W,
        int dcol, int kc, float4& A0, float4& A1, float4& A2, float4& A3)
{
    #pragma unroll 4
    for (int j = 0; j < 8; ++j) {
        const int k = j * 16 + kc;
        float4 x4;
        x4.x = xb[k]; x4.y = xb[xstr + k]; x4.z = xb[2 * xstr + k]; x4.w = xb[3 * xstr + k];
        const float* wr = W + (size_t)k * ND + dcol;
        float4 w4; w4.x = wr[0]; w4.y = wr[Dsz]; w4.z = wr[2 * Dsz]; w4.w = wr[3 * Dsz];
        FMA16(A0, A1, A2, A3, x4, w4)
    }
}
__device__ __forceinline__ void hpart_raw(const float* U, const float* XL2,
        int dcol, int kc, int qb, float4& A0, float4& A1, float4& A2, float4& A3)
{
    #pragma unroll 4
    for (int j = 0; j < 32; ++j) {
        const int k = j * 16 + kc;
        const float4 x4 = ldx4(XL2, k, qb);
        const float* wr = U + (size_t)k * ND + dcol;
        float4 w4; w4.x = wr[0]; w4.y = wr[Dsz]; w4.z = wr[2 * Dsz]; w4.w = wr[3 * Dsz];
        FMA16(A0, A1, A2, A3, x4, w4)
    }
}

__device__ __forceinline__ void red16(float4& a) {
    #pragma unroll
    for (int m = 1; m < 16; m <<= 1) {
        a.x += __shfl_xor(a.x, m, 64);
        a.y += __shfl_xor(a.y, m, 64);
        a.z += __shfl_xor(a.z, m, 64);
        a.w += __shfl_xor(a.w, m, 64);
    }
}
__device__ __forceinline__ float fin4(float4 z, float4 b4, float cprev, float& c2o) {
    float gi = sigf(z.x + b4.x);
    float gf = sigf(z.y + b4.y);
    float gg = fmaxf(z.z + b4.z, 0.f);
    float go = sigf(z.w + b4.w);
    float c2 = gf * cprev + gi * gg;
    c2o = c2;
    return go * fmaxf(c2, 0.f);
}
__device__ __forceinline__ float4 ldb4(const float* p, int d) {
    float4 r; r.x = p[d]; r.y = p[Dsz + d]; r.z = p[2 * Dsz + d]; r.w = p[3 * Dsz + d];
    return r;
}

// fused dense-row partials: out[b][fcol] = sum_k h[k][b]*dwT[fcol][k]
__device__ __forceinline__ void out_part_n(const float* XL2, const float* DWL, float* ORED,
                                           int kc, int qb, int wv)
{
    const int ff = wv & 3, qk = wv >> 2;
    float o0 = 0.f, o1 = 0.f, o2 = 0.f, o3 = 0.f;
    #pragma unroll
    for (int j = 0; j < 8; ++j) {
        const int k = qk * 128 + j * 16 + kc;
        const float wval = DWL[ff * 512 + k];
        const float4 x4 = ldx4(XL2, k, qb);
        o0 += x4.x * wval; o1 += x4.y * wval; o2 += x4.z * wval; o3 += x4.w * wval;
    }
    #pragma unroll
    for (int m = 1; m < 16; m <<= 1) {
        o0 += __shfl_xor(o0, m, 64); o1 += __shfl_xor(o1, m, 64);
        o2 += __shfl_xor(o2, m, 64); o3 += __shfl_xor(o3, m, 64);
    }
    if (kc == 0) {
        ORED[(qb * 4 + 0) * 16 + ff * 4 + qk] = o0;
        ORED[(qb * 4 + 1) * 16 + ff * 4 + qk] = o1;
        ORED[(qb * 4 + 2) * 16 + ff * 4 + qk] = o2;
        ORED[(qb * 4 + 3) * 16 + ff * 4 + qk] = o3;
    }
}

__global__ void __launch_bounds__(NTHR, 4)
lstm_ae_v7(const float* enc_in, const float* dec_in,
           const float* eW0, const float* eU0, const float* eb0,
           const float* eW1, const float* eU1, const float* eb1,
           const float* dW0, const float* dU0, const float* db0,
           const float* dW1, const float* dU1, const float* db1,
           const float* dw, const float* db_, float* out, float* ws)
{
    __shared__ float XL2[1024 * NSX];   // 81920 B, h/hA transposed [k][16b] swizzled
    __shared__ float WBA[128 * NWR];    // 34816 B weight chunk buffer A
    __shared__ float WBB[128 * NWR];    // 34816 B weight chunk buffer B
    __shared__ float DWL[4 * 512];      // 8192 B resident dwT slice (4 fcols)
    __shared__ float ORED[256];         // 1024 B

    unsigned* fslots = (unsigned*)ws;
    float* HT[2] = { ws + OFF_HT0, ws + OFF_HT1 };
    float* HMT = ws + OFF_HMT;

    const int blkid = blockIdx.x;
    const int grp  = blkid & 7;
    const int mem  = blkid >> 3;
    const int sgrp = mem & 7;
    const int dslc = mem >> 3;
    const int gm   = dslc * 8 + grp;
    unsigned* gslots = (unsigned*)ws + 256 + sgrp * 64;

    const int tid  = threadIdx.x;
    const int wv   = tid >> 6;
    const int lane = tid & 63;
    const int qb   = lane >> 4;          // sample quad 0..3
    const int kc   = lane & 15;          // K interleave slot
    const int dcol = grp * 64 + dslc * 16 + wv;
    const int dblk = grp * 4 + dslc;     // 16-dcol block id 0..31
    const int row0 = sgrp * 16;
    const int fcol0 = grp * 16 + dslc * 4;
    const int gid  = blkid * NTHR + tid;
    const int bfin = qb * 4 + kc;        // valid when kc<4

    float* nEW0  = ws + OFF_N_EW0;
    float* nEU0  = ws + OFF_N_EU0;
    float* nWSUM = ws + OFF_N_WSUM;
    float* nWDECA= ws + OFF_N_WDECA;
    float* nDCAT = ws + OFF_N_DCAT;
    float* nBF   = ws + OFF_N_BF;
    float* nDWT  = ws + OFF_N_DWT;

    // ---------------- P0: pack weights into LDS-image layout ----------------
    {   // EW0p: 32*128*64 = 262144 -> exactly 1/thread
        const int u = gid;
        const int db = u >> 13, k = (u >> 6) & 127, c = u & 63;
        nEW0[db * 8704 + k * NWR + c] =
            eW0[(size_t)k * ND + (size_t)(c & 3) * Dsz + db * 16 + (c >> 2)];
    }
    for (int u = gid; u < (1 << 20); u += NBLK * NTHR) {   // EU0p + WSUMp
        const int db = u >> 15, r = (u >> 6) & 511, c = u & 63;
        const size_t s = (size_t)r * ND + (size_t)(c & 3) * Dsz + db * 16 + (c >> 2);
        nEU0[db * 34816 + r * NWR + c]  = eU0[s];
        nWSUM[db * 34816 + r * NWR + c] = eW1[s] + eU1[s];
    }
    for (int u = gid; u < (1 << 21); u += NBLK * NTHR) {   // DCATp: rows<512=dU1, >=512=dW1
        const int db = u >> 16, r = (u >> 6) & 1023, c = u & 63;
        const size_t cs = (size_t)(c & 3) * Dsz + db * 16 + (c >> 2);
        float v = (r < 512) ? dU1[(size_t)r * ND + cs]
                            : dW1[(size_t)(r - 512) * ND + cs];
        nDCAT[db * 69632 + r * NWR + c] = v;
    }
    {   // WDECAp fold: dU0 + dw @ dW0 : 32*512*16 = 262144 quads, 1/thread
        const int u = gid;
        const int db = u >> 13, r = (u >> 4) & 511, w = u & 15;
        const int col = db * 16 + w;
        float a0 = dU0[(size_t)r * ND + col];
        float a1 = dU0[(size_t)r * ND + Dsz + col];
        float a2 = dU0[(size_t)r * ND + 2 * Dsz + col];
        float a3 = dU0[(size_t)r * ND + 3 * Dsz + col];
        const float* dwr = dw + (size_t)r * Fsz;
        for (int j = 0; j < Fsz; ++j) {
            const float wl = dwr[j];
            const float* dr = dW0 + (size_t)j * ND + col;
            a0 += wl * dr[0]; a1 += wl * dr[Dsz];
            a2 += wl * dr[2 * Dsz]; a3 += wl * dr[3 * Dsz];
        }
        float* dst = nWDECA + db * 34816 + r * NWR + w * 4;
        dst[0] = a0; dst[1] = a1; dst[2] = a2; dst[3] = a3;
    }
    if (gid < ND) {                                         // folded bias
        float acc = db0[gid];
        for (int j = 0; j < Fsz; ++j) acc += db_[j] * dW0[(size_t)j * ND + gid];
        nBF[gid] = acc;
    }
    if (gid < Dsz * Fsz) {                                  // dwT
        const int f = gid >> 9, k = gid & 511;
        nDWT[f * 512 + k] = dw[(size_t)k * Fsz + f];
    }
    gbar_all(fslots, blkid, 1);

    // resident dwT slice for this block's 4 fcols
    #pragma unroll
    for (int ii = 0; ii < 2; ++ii) {
        const int i = tid + ii * NTHR;
        DWL[i] = nDWT[(fcol0 + (i >> 9)) * 512 + (i & 511)];
    }
    __syncthreads();

    const float4 be0 = ldb4(eb0, dcol);
    const float4 be1 = ldb4(eb1, dcol);
    const float4 bd0 = ldb4(db0, dcol);
    const float4 bd1 = ldb4(db1, dcol);
    const float4 bfd = ldb4(nBF, dcol);

    const float* wEW0   = nEW0 + dblk * 8704;
    const float* wEU0   = nEU0 + dblk * 34816;
    const float* wWSUM  = nWSUM + dblk * 34816;
    const float* wWDECA = nWDECA + dblk * 34816;
    const float* wDCAT  = nDCAT + dblk * 69632;

    unsigned ep = 0;
    int cur = 0;
    float c_car = 0.f, c_mid = 0.f;
    const float4 Z4 = make_float4(0.f, 0.f, 0.f, 0.f);

    // ======================= encoder =======================
    for (int t = 0; t < Tsz; ++t) {
        // ---- L0 ----
        wchunk_to(wEW0, 0, WBA, tid);
        __syncthreads();
        float4 A0 = Z4, A1 = Z4, A2 = Z4, A3 = Z4;
        // EU0 chunk0 into regs (flies across x-part + wait)
        const float4* G0 = (const float4*)wEU0;
        float4 p0 = G0[tid], p1 = G0[1024 + tid], p2 = p0;
        if (tid < 128) p2 = G0[2048 + tid];
        xpart128(enc_in + (size_t)(row0 + qb * 4) * (Tsz * Fsz) + (size_t)t * Fsz,
                 Tsz * Fsz, WBA, kc, wv, A0, A1, A2, A3);
        wait_grp(gslots, ep);
        stageHn(XL2, HT[cur], row0, 0);
        { float4* L = (float4*)WBB; L[tid] = p0; L[1024 + tid] = p1;
          if (tid < 128) L[2048 + tid] = p2; }
        __syncthreads();
        mat_stream<4, 1>(wEU0, WBA, WBB, tid, XL2, kc, qb, wv, A0, A1, A2, A3);
        red16(A0); red16(A1); red16(A2); red16(A3);
        if (kc < 4) {
            float4 z = (kc == 0) ? A0 : (kc == 1) ? A1 : (kc == 2) ? A2 : A3;
            float cn; float h2 = fin4(z, be0, c_car, cn); c_mid = cn;
            st_coh(&HMT[(size_t)dcol * Bsz + row0 + bfin], h2);
        }
        arrive(&gslots[gm], ++ep);

        // ---- L1 (h1 @ (W1+U1)) ----
        const float4* G1 = (const float4*)wWSUM;
        p0 = G1[tid]; p1 = G1[1024 + tid]; p2 = p0;
        if (tid < 128) p2 = G1[2048 + tid];
        wait_grp(gslots, ep);
        stageHn(XL2, HMT, row0, 0);
        { float4* L = (float4*)WBA; L[tid] = p0; L[1024 + tid] = p1;
          if (tid < 128) L[2048 + tid] = p2; }
        __syncthreads();
        A0 = Z4; A1 = Z4; A2 = Z4; A3 = Z4;
        mat_stream<4, 0>(wWSUM, WBA, WBB, tid, XL2, kc, qb, wv, A0, A1, A2, A3);
        red16(A0); red16(A1); red16(A2); red16(A3);
        if (kc < 4) {
            float4 z = (kc == 0) ? A0 : (kc == 1) ? A1 : (kc == 2) ? A2 : A3;
            float cn; float h2 = fin4(z, be1, c_mid, cn); c_car = cn;
            st_coh(&HT[cur ^ 1][(size_t)dcol * Bsz + row0 + bfin], h2);
        }
        arrive(&gslots[gm], ++ep);
        cur ^= 1;
    }

    // ======================= decoder t=0 (slow raw path, one-time) =======================
    {
        float4 A0 = Z4, A1 = Z4, A2 = Z4, A3 = Z4;
        xpart_raw(dec_in + (size_t)(row0 + qb * 4) * (Tsz * Fsz), Tsz * Fsz,
                  dW0, dcol, kc, A0, A1, A2, A3);
        wait_grp(gslots, ep);
        stageHn(XL2, HT[cur], row0, 0);
        __syncthreads();
        hpart_raw(dU0, XL2, dcol, kc, qb, A0, A1, A2, A3);
        red16(A0); red16(A1); red16(A2); red16(A3);
        if (kc < 4) {
            float4 z = (kc == 0) ? A0 : (kc == 1) ? A1 : (kc == 2) ? A2 : A3;
            float cn; float h2 = fin4(z, bd0, c_car, cn);      // c discarded
            st_coh(&HMT[(size_t)dcol * Bsz + row0 + bfin], h2);
        }
        arrive(&gslots[gm], ++ep);
        // L1: [h_old ; hA] @ DCAT, old carry
        const float4* Gc = (const float4*)wDCAT;
        float4 p0 = Gc[tid], p1 = Gc[1024 + tid], p2 = p0;
        if (tid < 128) p2 = Gc[2048 + tid];
        wait_grp(gslots, ep);
        stageHn(XL2, HT[cur], row0, 0);
        stageHn(XL2, HMT, row0, 512);
        { float4* L = (float4*)WBA; L[tid] = p0; L[1024 + tid] = p1;
          if (tid < 128) L[2048 + tid] = p2; }
        __syncthreads();
        A0 = Z4; A1 = Z4; A2 = Z4; A3 = Z4;
        mat_stream<8, 0>(wDCAT, WBA, WBB, tid, XL2, kc, qb, wv, A0, A1, A2, A3);
        red16(A0); red16(A1); red16(A2); red16(A3);
        if (kc < 4) {
            float4 z = (kc == 0) ? A0 : (kc == 1) ? A1 : (kc == 2) ? A2 : A3;
            float cn; float h2 = fin4(z, bd1, c_car, cn); c_car = cn;
            st_coh(&HT[cur ^ 1][(size_t)dcol * Bsz + row0 + bfin], h2);
        }
        arrive(&gslots[gm], ++ep);
        cur ^= 1;
    }

    // ======================= decoder t=1..127 =======================
    for (int t = 1; t < Tsz; ++t) {
        const int tt = Tsz - t;
        // ---- L0 folded (h @ WDECA + bfold) + fused out partials ----
        const float4* Ga = (const float4*)wWDECA;
        float4 p0 = Ga[tid], p1 = Ga[1024 + tid], p2 = p0;
        if (tid < 128) p2 = Ga[2048 + tid];
        wait_grp(gslots, ep);
        stageHn(XL2, HT[cur], row0, 0);
        { float4* L = (float4*)WBA; L[tid] = p0; L[1024 + tid] = p1;
          if (tid < 128) L[2048 + tid] = p2; }
        __syncthreads();
        float4 A0 = Z4, A1 = Z4, A2 = Z4, A3 = Z4;
        mat_stream<4, 0>(wWDECA, WBA, WBB, tid, XL2, kc, qb, wv, A0, A1, A2, A3);
        out_part_n(XL2, DWL, ORED, kc, qb, wv);
        red16(A0); red16(A1); red16(A2); red16(A3);
        if (kc < 4) {
            float4 z = (kc == 0) ? A0 : (kc == 1) ? A1 : (kc == 2) ? A2 : A3;
            float cn; float h2 = fin4(z, bfd, c_car, cn);      // c discarded
            st_coh(&HMT[(size_t)dcol * Bsz + row0 + bfin], h2);
        }
        arrive(&gslots[gm], ++ep);
        if (tid < 64) {        // out row emit off the critical path
            const int bb = tid >> 2, ff = tid & 3;
            const int fc = fcol0 + ff;
            const float* r = ORED + bb * 16 + ff * 4;
            float s = r[0] + r[1] + r[2] + r[3] + db_[fc];
            out[((size_t)(row0 + bb) * Tsz + tt) * Fsz + fc] = s;
        }
        // ---- L1: [h ; hA] @ DCAT ----
        const float4* Gc = (const float4*)wDCAT;
        p0 = Gc[tid]; p1 = Gc[1024 + tid]; p2 = p0;
        if (tid < 128) p2 = Gc[2048 + tid];
        wait_grp(gslots, ep);
        stageHn(XL2, HMT, row0, 512);            // h rows 0..511 still valid
        { float4* L = (float4*)WBA; L[tid] = p0; L[1024 + tid] = p1;
          if (tid < 128) L[2048 + tid] = p2; }
        __syncthreads();
        A0 = Z4; A1 = Z4; A2 = Z4; A3 = Z4;
        mat_stream<8, 0>(wDCAT, WBA, WBB, tid, XL2, kc, qb, wv, A0, A1, A2, A3);
        red16(A0); red16(A1); red16(A2); red16(A3);
        if (kc < 4) {
            float4 z = (kc == 0) ? A0 : (kc == 1) ? A1 : (kc == 2) ? A2 : A3;
            float cn; float h2 = fin4(z, bd1, c_car, cn); c_car = cn;
            st_coh(&HT[cur ^ 1][(size_t)dcol * Bsz + row0 + bfin], h2);
        }
        arrive(&gslots[gm], ++ep);
        cur ^= 1;
    }

    // ======================= final out_127 -> row 0 =======================
    wait_grp(gslots, ep);
    stageHn(XL2, HT[cur], row0, 0);
    __syncthreads();
    out_part_n(XL2, DWL, ORED, kc, qb, wv);
    __syncthreads();
    if (tid < 64) {
        const int bb = tid >> 2, ff = tid & 3;
        const int fc = fcol0 + ff;
        const float* r = ORED + bb * 16 + ff * 4;
        float s = r[0] + r[1] + r[2] + r[3] + db_[fc];
        out[((size_t)(row0 + bb) * Tsz + 0) * Fsz + fc] = s;
    }
}

// =====================================================================
// ======================  v6 fallback kernel  =========================
// =====================================================================

__device__ __forceinline__ void stage_vec(float* XL, int xstr, int dstoff,
        const float* src, int row0, int ld, int klen, int c4shift) {
    const int q = klen >> 2;
    const int n4 = q * 16;
    for (int i = threadIdx.x; i < n4; i += NTHR) {
        const int row = i >> c4shift;
        const int c4 = i & (q - 1);
        float4 v = *(const float4*)(src + (size_t)(row0 + row) * ld + (c4 << 2));
        *(float4*)(XL + row * xstr + dstoff + (c4 << 2)) = v;
    }
}
__device__ __forceinline__ void stage_coh_T(float* XL, int xstr, int dstoff,
        const float* HTsrc, int row0) {
    for (int i = threadIdx.x; i < Dsz * 16; i += NTHR) {
        const int d = i >> 4;
        const int bb = i & 15;
        XL[bb * xstr + dstoff + d] = ld_coh(HTsrc + (size_t)d * Bsz + row0 + bb);
    }
}
__device__ __forceinline__ void acc_seg(float4& z, const float* xp,
                                        const float4* wp, int ksub) {
    #pragma unroll 4
    for (int j = 0; j < ksub; j += 4) {
        float4 x4 = *(const float4*)(xp + j);
        float4 w0 = wp[j], w1 = wp[j + 1], w2 = wp[j + 2], w3 = wp[j + 3];
        z.x += x4.x*w0.x + x4.y*w1.x + x4.z*w2.x + x4.w*w3.x;
        z.y += x4.x*w0.y + x4.y*w1.y + x4.z*w2.y + x4.w*w3.y;
        z.z += x4.x*w0.z + x4.y*w1.z + x4.z*w2.z + x4.w*w3.z;
        z.w += x4.x*w0.w + x4.y*w1.w + x4.z*w2.w + x4.w*w3.w;
    }
}
__device__ __forceinline__ void acc_segS(float4& z, const float* xp,
                                         const float* W, int kbase, int ksub, int dcol) {
    for (int j = 0; j < ksub; ++j) {
        const float x = xp[j];
        const float* wr = W + (size_t)(kbase + j) * ND + dcol;
        z.x += x * wr[0];
        z.y += x * wr[Dsz];
        z.z += x * wr[2 * Dsz];
        z.w += x * wr[3 * Dsz];
    }
}
__device__ __forceinline__ void reduce4(float4& z) {
    z.x += __shfl_xor(z.x, 16); z.x += __shfl_xor(z.x, 32);
    z.y += __shfl_xor(z.y, 16); z.y += __shfl_xor(z.y, 32);
    z.z += __shfl_xor(z.z, 16); z.z += __shfl_xor(z.z, 32);
    z.w += __shfl_xor(z.w, 16); z.w += __shfl_xor(z.w, 32);
}
__device__ __forceinline__ float lstm_fin(float4 z, const float* bias, int dcol,
                                          float cprev, float& c2out) {
    float gi = sigf(z.x + bias[dcol]);
    float gf = sigf(z.y + bias[Dsz + dcol]);
    float gg = fmaxf(z.z + bias[2 * Dsz + dcol], 0.f);
    float go = sigf(z.w + bias[3 * Dsz + dcol]);
    float c2 = gf * cprev + gi * gg;
    c2out = c2;
    return go * fmaxf(c2, 0.f);
}
__device__ __forceinline__ void out_part(const float* XL, int xstr, float* ORED,
                                         int b, int kc, int w, int fcol,
                                         const float* dwT) {
    const int q = w >> 2;
    const float* xp = XL + b * xstr + q * 128 + kc * 32;
    const float* wt = dwT + (size_t)fcol * Dsz + q * 128 + kc * 32;
    float acc = 0.f;
    #pragma unroll
    for (int j = 0; j < 32; j += 4) {
        float4 x4 = *(const float4*)(xp + j);
        float4 w4 = *(const float4*)(wt + j);
        acc += x4.x * w4.x + x4.y * w4.y + x4.z * w4.z + x4.w * w4.w;
    }
    acc += __shfl_xor(acc, 16); acc += __shfl_xor(acc, 32);
    if ((threadIdx.x & 63) < 16) ORED[b * 16 + (w & 3) * 4 + q] = acc;
}
__device__ void pack_gate(float* dst, const float* src, int K, int kshift, int gid) {
    const int total = K * Dsz;
    for (int u = gid; u < total; u += NBLK * NTHR) {
        const int dd = u >> kshift;
        const int k = u & (K - 1);
        const float* sp = src + (size_t)k * ND + dd;
        ((float4*)dst)[u] = make_float4(sp[0], sp[Dsz], sp[2 * Dsz], sp[3 * Dsz]);
    }
}
__device__ void pack_wsum(float* dst, const float* a, const float* bsrc, int gid) {
    for (int u = gid; u < Dsz * Dsz; u += NBLK * NTHR) {
        const int dd = u >> 9, k = u & 511;
        const float* pa = a + (size_t)k * ND + dd;
        const float* pb = bsrc + (size_t)k * ND + dd;
        ((float4*)dst)[u] = make_float4(pa[0] + pb[0], pa[Dsz] + pb[Dsz],
                                        pa[2*Dsz] + pb[2*Dsz], pa[3*Dsz] + pb[3*Dsz]);
    }
}
__device__ void pack_wdeca_p(float* dst, const float* dU0, const float* dW0,
                             const float* dw, int gid) {
    for (int u = gid; u < Dsz * Dsz; u += NBLK * NTHR) {
        const int dd = u >> 9, k = u & 511;
        const float* pu = dU0 + (size_t)k * ND + dd;
        float a0 = pu[0], a1 = pu[Dsz], a2 = pu[2*Dsz], a3 = pu[3*Dsz];
        const float* dwr = dw + k * Fsz;
        for (int j = 0; j < Fsz; ++j) {
            const float wv = dwr[j];
            const float* dr = dW0 + (size_t)j * ND + dd;
            a0 += wv * dr[0]; a1 += wv * dr[Dsz];
            a2 += wv * dr[2*Dsz]; a3 += wv * dr[3*Dsz];
        }
        ((float4*)dst)[u] = make_float4(a0, a1, a2, a3);
    }
}

template<bool PACKED>
__global__ void __launch_bounds__(NTHR, 1)
lstm_ae_kernel(const float* enc_in, const float* dec_in,
               const float* eW0, const float* eU0, const float* eb0,
               const float* eW1, const float* eU1, const float* eb1,
               const float* dW0, const float* dU0, const float* db0,
               const float* dW1, const float* dU1, const float* db1,
               const float* dw, const float* db_, float* out, float* ws)
{
    __shared__ float XL[16 * 1028];
    __shared__ float ORED[256];

    unsigned* fslots = (unsigned*)ws;
    float* HT[2] = { ws + OFF_HT0, ws + OFF_HT1 };
    float* HMT = ws + OFF_HMT;

    const int blkid = blockIdx.x;
    const int grp  = blkid & 7;
    const int mem  = blkid >> 3;
    const int sgrp = mem & 7;
    const int dslc = mem >> 3;
    const int gm   = dslc * 8 + grp;
    unsigned* gslots = (unsigned*)ws + 256 + sgrp * 64;

    const int tid  = threadIdx.x;
    const int w    = tid >> 6;
    const int lane = tid & 63;
    const int b    = lane & 15;
    const int kc   = lane >> 4;
    const int dcol = grp * 64 + dslc * 16 + w;
    const int bgl  = sgrp * 16 + b;
    const int row0 = sgrp * 16;
    const int fcol = grp * 16 + dslc * 4 + (w & 3);
    const int gid  = blkid * NTHR + tid;

    const float *pEW0, *pEU0, *pWSUM, *pWDECA, *pDW0, *pDU0, *pDW1, *pDU1, *pBF, *pDWT;

    if (PACKED) {
        pack_gate(ws + OFF_P_EW0, eW0, Fsz, 7, gid);
        pack_gate(ws + OFF_P_EU0, eU0, Dsz, 9, gid);
        pack_wsum(ws + OFF_P_WSUM, eW1, eU1, gid);
        pack_wdeca_p(ws + OFF_P_WDECA, dU0, dW0, dw, gid);
        pack_gate(ws + OFF_P_DW0, dW0, Fsz, 7, gid);
        pack_gate(ws + OFF_P_DU0, dU0, Dsz, 9, gid);
        pack_gate(ws + OFF_P_DW1, dW1, Dsz, 9, gid);
        pack_gate(ws + OFF_P_DU1, dU1, Dsz, 9, gid);
        if (gid < ND) {
            float acc = db0[gid];
            for (int j = 0; j < Fsz; ++j) acc += db_[j] * dW0[(size_t)j * ND + gid];
            (ws + OFF_P_BF)[gid] = acc;
        }
        if (gid < Dsz * Fsz) {
            const int f = gid >> 9, k = gid & 511;
            (ws + OFF_P_DWT)[(size_t)f * Dsz + k] = dw[(size_t)k * Fsz + f];
        }
        pEW0 = ws + OFF_P_EW0; pEU0 = ws + OFF_P_EU0; pWSUM = ws + OFF_P_WSUM;
        pWDECA = ws + OFF_P_WDECA; pDW0 = ws + OFF_P_DW0; pDU0 = ws + OFF_P_DU0;
        pDW1 = ws + OFF_P_DW1; pDU1 = ws + OFF_P_DU1; pBF = ws + OFF_P_BF;
        pDWT = ws + OFF_P_DWT;
    } else {
        pack_wsum(ws + OFF_F_WSUM, eW1, eU1, gid);
        pack_wdeca_p(ws + OFF_F_WDECA, dU0, dW0, dw, gid);
        if (gid < ND) {
            float acc = db0[gid];
            for (int j = 0; j < Fsz; ++j) acc += db_[j] * dW0[(size_t)j * ND + gid];
            (ws + OFF_F_BF)[gid] = acc;
        }
        if (gid < Dsz * Fsz) {
            const int f = gid >> 9, k = gid & 511;
            (ws + OFF_F_DWT)[(size_t)f * Dsz + k] = dw[(size_t)k * Fsz + f];
        }
        pEW0 = eW0; pEU0 = eU0; pWSUM = ws + OFF_F_WSUM;
        pWDECA = ws + OFF_F_WDECA; pDW0 = dW0; pDU0 = dU0;
        pDW1 = dW1; pDU1 = dU1; pBF = ws + OFF_F_BF;
        pDWT = ws + OFF_F_DWT;
    }
    gbar_all(fslots, blkid, 1);

    unsigned ep = 0;
    int cur = 0;
    float c_car = 0.f;

    for (int t = 0; t < Tsz; ++t) {
        stage_vec(XL, 644, 0, enc_in + (size_t)t * Fsz, row0, Tsz * Fsz, 128, 5);
        __syncthreads();
        float4 z = make_float4(0.f, 0.f, 0.f, 0.f);
        if (PACKED) acc_seg(z, XL + b * 644 + kc * 32,
                            (const float4*)pEW0 + (size_t)dcol * 128 + kc * 32, 32);
        else        acc_segS(z, XL + b * 644 + kc * 32, pEW0, kc * 32, 32, dcol);
        wait_grp(gslots, ep);
        stage_coh_T(XL, 644, 128, HT[cur], row0);
        __syncthreads();
        if (PACKED) acc_seg(z, XL + b * 644 + 128 + kc * 128,
                            (const float4*)pEU0 + (size_t)dcol * 512 + kc * 128, 128);
        else        acc_segS(z, XL + b * 644 + 128 + kc * 128, pEU0, kc * 128, 128, dcol);
        reduce4(z);
        float c1 = 0.f;
        if (lane < 16) {
            float h2 = lstm_fin(z, eb0, dcol, c_car, c1);
            st_coh(&HMT[(size_t)dcol * Bsz + bgl], h2);
        }
        arrive(&gslots[gm], ++ep);
        wait_grp(gslots, ep);
        stage_coh_T(XL, 516, 0, HMT, row0);
        __syncthreads();
        z = make_float4(0.f, 0.f, 0.f, 0.f);
        acc_seg(z, XL + b * 516 + kc * 128,
                (const float4*)pWSUM + (size_t)dcol * 512 + kc * 128, 128);
        reduce4(z);
        if (lane < 16) {
            float c2;
            float h2 = lstm_fin(z, eb1, dcol, c1, c2);
            c_car = c2;
            st_coh(&HT[cur ^ 1][(size_t)dcol * Bsz + bgl], h2);
        }
        arrive(&gslots[gm], ++ep);
        cur ^= 1;
    }

    stage_vec(XL, 644, 0, dec_in, row0, Tsz * Fsz, 128, 5);
    __syncthreads();
    {
        float4 z = make_float4(0.f, 0.f, 0.f, 0.f);
        if (PACKED) acc_seg(z, XL + b * 644 + kc * 32,
                            (const float4*)pDW0 + (size_t)dcol * 128 + kc * 32, 32);
        else        acc_segS(z, XL + b * 644 + kc * 32, pDW0, kc * 32, 32, dcol);
        wait_grp(gslots, ep);
        stage_coh_T(XL, 644, 128, HT[cur], row0);
        __syncthreads();
        if (PACKED) acc_seg(z, XL + b * 644 + 128 + kc * 128,
                            (const float4*)pDU0 + (size_t)dcol * 512 + kc * 128, 128);
        else        acc_segS(z, XL + b * 644 + 128 + kc * 128, pDU0, kc * 128, 128, dcol);
        reduce4(z);
        if (lane < 16) {
            float cd;
            float h2 = lstm_fin(z, db0, dcol, c_car, cd);
            st_coh(&HMT[(size_t)dcol * Bsz + bgl], h2);
        }
        arrive(&gslots[gm], ++ep);
    }
    wait_grp(gslots, ep);
    stage_coh_T(XL, 1028, 0, HT[cur], row0);
    stage_coh_T(XL, 1028, 512, HMT, row0);
    __syncthreads();
    {
        float4 z = make_float4(0.f, 0.f, 0.f, 0.f);
        if (PACKED) {
            acc_seg(z, XL + b * 1028 + kc * 128,
                    (const float4*)pDU1 + (size_t)dcol * 512 + kc * 128, 128);
            acc_seg(z, XL + b * 1028 + 512 + kc * 128,
                    (const float4*)pDW1 + (size_t)dcol * 512 + kc * 128, 128);
        } else {
            acc_segS(z, XL + b * 1028 + kc * 128, pDU1, kc * 128, 128, dcol);
            acc_segS(z, XL + b * 1028 + 512 + kc * 128, pDW1, kc * 128, 128, dcol);
        }
        reduce4(z);
        if (lane < 16) {
            float c2;
            float h2 = lstm_fin(z, db1, dcol, c_car, c2);
            c_car = c2;
            st_coh(&HT[cur ^ 1][(size_t)dcol * Bsz + bgl], h2);
        }
    }
    arrive(&gslots[gm], ++ep);
    cur ^= 1;

    for (int t = 1; t < Tsz; ++t) {
        const int tt = Tsz - t;
        wait_grp(gslots, ep);
        stage_coh_T(XL, 1028, 0, HT[cur], row0);
        __syncthreads();
        {
            float4 z = make_float4(0.f, 0.f, 0.f, 0.f);
            acc_seg(z, XL + b * 1028 + kc * 128,
                    (const float4*)pWDECA + (size_t)dcol * 512 + kc * 128, 128);
            reduce4(z);
            out_part(XL, 1028, ORED, b, kc, w, fcol, pDWT);
            if (lane < 16) {
                float cd;
                float h2 = lstm_fin(z, pBF, dcol, c_car, cd);
                st_coh(&HMT[(size_t)dcol * Bsz + bgl], h2);
            }
        }
        arrive(&gslots[gm], ++ep);
        if (tid < 64) {
            const int bb = tid >> 2, ff = tid & 3;
            const int fc = grp * 16 + dslc * 4 + ff;
            const float* r = ORED + bb * 16 + ff * 4;
            float s = r[0] + r[1] + r[2] + r[3] + db_[fc];
            out[((size_t)(row0 + bb) * Tsz + tt) * Fsz + fc] = s;
        }
        wait_grp(gslots, ep);
        stage_coh_T(XL, 1028, 512, HMT, row0);
        __syncthreads();
        {
            float4 z = make_float4(0.f, 0.f, 0.f, 0.f);
            if (PACKED) {
                acc_seg(z, XL + b * 1028 + kc * 128,
                        (const float4*)pDU1 + (size_t)dcol * 512 + kc * 128, 128);
                acc_seg(z, XL + b * 1028 + 512 + kc * 128,
                        (const float4*)pDW1 + (size_t)dcol * 512 + kc * 128, 128);
            } else {
                acc_segS(z, XL + b * 1028 + kc * 128, pDU1, kc * 128, 128, dcol);
                acc_segS(z, XL + b * 1028 + 512 + kc * 128, pDW1, kc * 128, 128, dcol);
            }
            reduce4(z);
            if (lane < 16) {
                float c2;
                float h2 = lstm_fin(z, db1, dcol, c_car, c2);
                c_car = c2;
                st_coh(&HT[cur ^ 1][(size_t)dcol * Bsz + bgl], h2);
            }
        }
        arrive(&gslots[gm], ++ep);
        cur ^= 1;
    }

    wait_grp(gslots, ep);
    stage_coh_T(XL, 516, 0, HT[cur], row0);
    __syncthreads();
    out_part(XL, 516, ORED, b, kc, w, fcol, pDWT);
    __syncthreads();
    if (tid < 64) {
        const int bb = tid >> 2, ff = tid & 3;
        const int fc = grp * 16 + dslc * 4 + ff;
        const float* r = ORED + bb * 16 + ff * 4;
        float s = r[0] + r[1] + r[2] + r[3] + db_[fc];
        out[((size_t)(row0 + bb) * Tsz + 0) * Fsz + fc] = s;
    }
}

extern "C" void kernel_launch(void* const* d_in, const int* in_sizes, int n_in,
                              void* d_out, int out_size, void* d_ws, size_t ws_size,
                              hipStream_t stream) {
    (void)in_sizes; (void)n_in; (void)out_size;
    const float* enc_in = (const float*)d_in[0];
    const float* dec_in = (const float*)d_in[1];
    const float* eW0 = (const float*)d_in[2];
    const float* eU0 = (const float*)d_in[3];
    const float* eb0 = (const float*)d_in[4];
    const float* eW1 = (const float*)d_in[5];
    const float* eU1 = (const float*)d_in[6];
    const float* eb1 = (const float*)d_in[7];
    const float* dW0 = (const float*)d_in[8];
    const float* dU0 = (const float*)d_in[9];
    const float* db0 = (const float*)d_in[10];
    const float* dW1 = (const float*)d_in[11];
    const float* dU1 = (const float*)d_in[12];
    const float* db1 = (const float*)d_in[13];
    const float* dw  = (const float*)d_in[14];
    const float* db_ = (const float*)d_in[15];
    float* out = (float*)d_out;
    float* ws = (float*)d_ws;

    // zero: barrier slots + HT0 (initial h = 0)
    hipMemsetAsync(d_ws, 0, (size_t)(OFF_HT0 + Dsz * Bsz) * sizeof(float), stream);

    if (ws_size >= (size_t)WS_N_FLOATS * sizeof(float))
        lstm_ae_v7<<<NBLK, NTHR, 0, stream>>>(
            enc_in, dec_in, eW0, eU0, eb0, eW1, eU1, eb1,
            dW0, dU0, db0, dW1, dU1, db1, dw, db_, out, ws);
    else if (ws_size >= (size_t)WS_PACKED_FLOATS * sizeof(float))
        lstm_ae_kernel<true><<<NBLK, NTHR, 0, stream>>>(
            enc_in, dec_in, eW0, eU0, eb0, eW1, eU1, eb1,
            dW0, dU0, db0, dW1, dU1, db1, dw, db_, out, ws);
    else
        lstm_ae_kernel<false><<<NBLK, NTHR, 0, stream>>>(
            enc_in, dec_in, eW0, eU0, eb0, eW1, eU1, eb1,
            dW0, dU0, db0, dW1, dU1, db1, dw, db_, out, ws);
}

// Round 2
// 12075.308 us; speedup vs baseline: 5.3364x; 5.3364x over previous
//
#include <hip/hip_runtime.h>

// =====================================================================
// LSTM autoencoder v8: v6 skeleton (P0 packing, ws layout, group
// barriers, launch_bounds(1024,1)) + 4x4-tiled consume path:
//  - lane (qb,kc): 4 samples (qb*4..+3) x 4 gates of one dcol, K split
//    16-way across kc, butterfly shfl reduce over kc.
//  - weight reads straight from L2-resident packed ws (NO LDS streaming,
//    NO prefetch reg triples -> tiny live set, no spills). Duplicated
//    weight loads drop 16-lane-dup -> 4-lane-dup; per-CU weight-load
//    instrs drop 4x; each b128 feeds 16 FMAs (was 4).
//  - h staged transposed [k][b] in LDS with quad-XOR swizzle.
// v6 fallback kernel retained for small workspaces.
// =====================================================================

#define Bsz 128
#define Tsz 128
#define Fsz 128
#define Dsz 512
#define ND  2048
#define NBLK 256
#define NTHR 1024

// ---- ws layout (float offsets) ----
#define OFF_HT0  1024
#define OFF_HT1  (OFF_HT0 + Dsz*Bsz)
#define OFF_HMT  (OFF_HT1 + Dsz*Bsz)
#define OFF_WEND (OFF_HMT + Dsz*Bsz)
// packed weights (gate-interleaved float4: Wp4[dcol*K + k] = {i,f,g,o})
#define OFF_P_EW0   OFF_WEND
#define OFF_P_EU0   (OFF_P_EW0 + Fsz*ND)
#define OFF_P_WSUM  (OFF_P_EU0 + Dsz*ND)
#define OFF_P_WDECA (OFF_P_WSUM + Dsz*ND)
#define OFF_P_DW0   (OFF_P_WDECA + Dsz*ND)
#define OFF_P_DU0   (OFF_P_DW0 + Fsz*ND)
#define OFF_P_DW1   (OFF_P_DU0 + Dsz*ND)
#define OFF_P_DU1   (OFF_P_DW1 + Dsz*ND)
#define OFF_P_BF    (OFF_P_DU1 + Dsz*ND)
#define OFF_P_DWT   (OFF_P_BF + ND)
#define WS_PACKED_FLOATS (OFF_P_DWT + Dsz*Fsz)
// fallback: only folded matrices packed; raw mats strided
#define OFF_F_WSUM  OFF_WEND
#define OFF_F_WDECA (OFF_F_WSUM + Dsz*ND)
#define OFF_F_BF    (OFF_F_WDECA + Dsz*ND)
#define OFF_F_DWT   (OFF_F_BF + ND)
#define WS_FALLBACK_FLOATS (OFF_F_DWT + Dsz*Fsz)

#define NSX 20   // LDS row stride (16 data + 4 pad), 16B-aligned rows

__device__ __forceinline__ float sigf(float x) {
    return 1.0f / (1.0f + __expf(-x));
}
__device__ __forceinline__ float ld_coh(const float* p) {
    return __hip_atomic_load((float*)p, __ATOMIC_RELAXED, __HIP_MEMORY_SCOPE_AGENT);
}
__device__ __forceinline__ void st_coh(float* p, float v) {
    __hip_atomic_store(p, v, __ATOMIC_RELAXED, __HIP_MEMORY_SCOPE_AGENT);
}

// ---- split group barrier (32 members) ----
__device__ __forceinline__ void arrive(unsigned* slot, unsigned ep) {
    __syncthreads();   // all waves' compute + coherent stores drained
    if (threadIdx.x == 0)
        __hip_atomic_store(slot, ep, __ATOMIC_RELEASE, __HIP_MEMORY_SCOPE_AGENT);
}
__device__ __forceinline__ void wait_grp(unsigned* gslots, unsigned ep) {
    if (threadIdx.x < 64) {
        for (;;) {
            unsigned v = (threadIdx.x < 32)
                ? __hip_atomic_load(&gslots[threadIdx.x], __ATOMIC_RELAXED,
                                    __HIP_MEMORY_SCOPE_AGENT)
                : ep;
            if (__all(v >= ep)) break;
            __builtin_amdgcn_s_sleep(1);
        }
    }
    __syncthreads();
}
__device__ __forceinline__ void gbar_all(unsigned* slots, int blkid, unsigned ep) {
    __syncthreads();
    if (threadIdx.x == 0) {
        __threadfence();
        __hip_atomic_store(&slots[blkid], ep, __ATOMIC_RELEASE,
                           __HIP_MEMORY_SCOPE_AGENT);
    }
    if (threadIdx.x < 64) {
        for (;;) {
            unsigned mn = ~0u;
            #pragma unroll
            for (int q = 0; q < 4; ++q) {
                unsigned v = __hip_atomic_load(&slots[threadIdx.x * 4 + q],
                                               __ATOMIC_RELAXED, __HIP_MEMORY_SCOPE_AGENT);
                mn = min(mn, v);
            }
            if (__all(mn >= ep)) break;
            __builtin_amdgcn_s_sleep(1);
        }
        if (threadIdx.x == 0) __threadfence();
    }
    __syncthreads();
}

// ---- P0 packing (identical to v6) ----
__device__ void pack_gate(float* dst, const float* src, int K, int kshift, int gid) {
    const int total = K * Dsz;
    for (int u = gid; u < total; u += NBLK * NTHR) {
        const int dd = u >> kshift;
        const int k = u & (K - 1);
        const float* sp = src + (size_t)k * ND + dd;
        ((float4*)dst)[u] = make_float4(sp[0], sp[Dsz], sp[2 * Dsz], sp[3 * Dsz]);
    }
}
__device__ void pack_wsum(float* dst, const float* a, const float* bsrc, int gid) {
    for (int u = gid; u < Dsz * Dsz; u += NBLK * NTHR) {
        const int dd = u >> 9, k = u & 511;
        const float* pa = a + (size_t)k * ND + dd;
        const float* pb = bsrc + (size_t)k * ND + dd;
        ((float4*)dst)[u] = make_float4(pa[0] + pb[0], pa[Dsz] + pb[Dsz],
                                        pa[2*Dsz] + pb[2*Dsz], pa[3*Dsz] + pb[3*Dsz]);
    }
}
__device__ void pack_wdeca_p(float* dst, const float* dU0, const float* dW0,
                             const float* dw, int gid) {
    for (int u = gid; u < Dsz * Dsz; u += NBLK * NTHR) {
        const int dd = u >> 9, k = u & 511;
        const float* pu = dU0 + (size_t)k * ND + dd;
        float a0 = pu[0], a1 = pu[Dsz], a2 = pu[2*Dsz], a3 = pu[3*Dsz];
        const float* dwr = dw + k * Fsz;
        for (int j = 0; j < Fsz; ++j) {
            const float wv = dwr[j];
            const float* dr = dW0 + (size_t)j * ND + dd;
            a0 += wv * dr[0]; a1 += wv * dr[Dsz];
            a2 += wv * dr[2*Dsz]; a3 += wv * dr[3*Dsz];
        }
        ((float4*)dst)[u] = make_float4(a0, a1, a2, a3);
    }
}

// =====================================================================
// ======================  v8 kernel  ==================================
// =====================================================================

__device__ __forceinline__ int swz3(int k) { return (k ^ (k >> 3)) & 3; }

__device__ __forceinline__ void stXrow(float* XL2, int k, int bb, float v) {
    XL2[k * NSX + ((((bb >> 2) ^ swz3(k)) << 2) | (bb & 3))] = v;
}
__device__ __forceinline__ float4 ldx4(const float* XL2, int k, int qb) {
    return *(const float4*)(XL2 + k * NSX + ((qb ^ swz3(k)) << 2));
}

// stage 512 h rows from transposed coherent buffer into XL2 rows rbase..+511
__device__ __forceinline__ void stageH(float* XL2, const float* HTsrc, int row0, int rbase) {
    #pragma unroll
    for (int ii = 0; ii < 8; ++ii) {
        const int i = (int)threadIdx.x + ii * NTHR;
        const int r = i >> 4, bb = i & 15;
        stXrow(XL2, rbase + r, bb, ld_coh(HTsrc + (size_t)r * Bsz + row0 + bb));
    }
}
// stage 128 x rows (row-major global, coalesced along k) into rows rbase..+127
__device__ __forceinline__ void stageX(float* XL2, const float* src, int row0, int rbase) {
    #pragma unroll
    for (int ii = 0; ii < 2; ++ii) {
        const int i = (int)threadIdx.x + ii * NTHR;
        const int bb = i >> 7, r = i & 127;
        stXrow(XL2, rbase + r, bb, src[(size_t)(row0 + bb) * (Tsz * Fsz) + r]);
    }
}

#define FMA16(A0,A1,A2,A3,x4,w4) \
    A0.x += x4.x*w4.x; A0.y += x4.x*w4.y; A0.z += x4.x*w4.z; A0.w += x4.x*w4.w; \
    A1.x += x4.y*w4.x; A1.y += x4.y*w4.y; A1.z += x4.y*w4.z; A1.w += x4.y*w4.w; \
    A2.x += x4.z*w4.x; A2.y += x4.z*w4.y; A2.z += x4.z*w4.z; A2.w += x4.z*w4.w; \
    A3.x += x4.w*w4.x; A3.y += x4.w*w4.y; A3.z += x4.w*w4.z; A3.w += x4.w*w4.w;

// consume NJ*16 rows: weights Wp[l] (l=0..NJ*16-1), x at XL2 rows kbase+l
template<int NJ>
__device__ __forceinline__ void consT(const float4* __restrict__ Wp,
        const float* __restrict__ XL2, int kbase, int kc, int qb,
        float4& A0, float4& A1, float4& A2, float4& A3)
{
    #pragma unroll 8
    for (int j = 0; j < NJ; ++j) {
        const int l = j * 16 + kc;
        const float4 x4 = ldx4(XL2, kbase + l, qb);
        const float4 w4 = Wp[l];
        FMA16(A0, A1, A2, A3, x4, w4)
    }
}

__device__ __forceinline__ void red16(float4& a) {
    #pragma unroll
    for (int m = 1; m < 16; m <<= 1) {
        a.x += __shfl_xor(a.x, m, 64);
        a.y += __shfl_xor(a.y, m, 64);
        a.z += __shfl_xor(a.z, m, 64);
        a.w += __shfl_xor(a.w, m, 64);
    }
}
__device__ __forceinline__ float fin4b(float4 z, const float* bias, int dcol,
                                       float cprev, float& c2o) {
    float gi = sigf(z.x + bias[dcol]);
    float gf = sigf(z.y + bias[Dsz + dcol]);
    float gg = fmaxf(z.z + bias[2 * Dsz + dcol], 0.f);
    float go = sigf(z.w + bias[3 * Dsz + dcol]);
    float c2 = gf * cprev + gi * gg;
    c2o = c2;
    return go * fmaxf(c2, 0.f);
}

// fused dense-row partials: out[b][fcol0+ff] += sum_k h[k][b]*dwT[fcol][k]
__device__ __forceinline__ void out_part_n(const float* XL2, const float* DWL, float* ORED,
                                           int kc, int qb, int wv)
{
    const int ff = wv & 3, qk = wv >> 2;
    float o0 = 0.f, o1 = 0.f, o2 = 0.f, o3 = 0.f;
    #pragma unroll
    for (int j = 0; j < 8; ++j) {
        const int k = qk * 128 + j * 16 + kc;
        const float wval = DWL[ff * 512 + k];
        const float4 x4 = ldx4(XL2, k, qb);
        o0 += x4.x * wval; o1 += x4.y * wval; o2 += x4.z * wval; o3 += x4.w * wval;
    }
    #pragma unroll
    for (int m = 1; m < 16; m <<= 1) {
        o0 += __shfl_xor(o0, m, 64); o1 += __shfl_xor(o1, m, 64);
        o2 += __shfl_xor(o2, m, 64); o3 += __shfl_xor(o3, m, 64);
    }
    if (kc == 0) {
        ORED[(qb * 4 + 0) * 16 + ff * 4 + qk] = o0;
        ORED[(qb * 4 + 1) * 16 + ff * 4 + qk] = o1;
        ORED[(qb * 4 + 2) * 16 + ff * 4 + qk] = o2;
        ORED[(qb * 4 + 3) * 16 + ff * 4 + qk] = o3;
    }
}

__global__ void __launch_bounds__(NTHR, 1)
lstm_ae_v8(const float* enc_in, const float* dec_in,
           const float* eW0, const float* eU0, const float* eb0,
           const float* eW1, const float* eU1, const float* eb1,
           const float* dW0, const float* dU0, const float* db0,
           const float* dW1, const float* dU1, const float* db1,
           const float* dw, const float* db_, float* out, float* ws)
{
    __shared__ float XL2[1024 * NSX];   // 81920 B transposed h/hA/x, swizzled
    __shared__ float DWL[4 * 512];      //  8192 B resident dwT slice (4 fcols)
    __shared__ float ORED[256];         //  1024 B

    unsigned* fslots = (unsigned*)ws;
    float* HT[2] = { ws + OFF_HT0, ws + OFF_HT1 };
    float* HMT = ws + OFF_HMT;

    const int blkid = blockIdx.x;
    const int grp  = blkid & 7;       // XCD / dcol-slice owner
    const int mem  = blkid >> 3;      // 0..31
    const int sgrp = mem & 7;         // sample group (barrier domain)
    const int dslc = mem >> 3;        // 0..3
    const int gm   = dslc * 8 + grp;  // member id within group (0..31)
    unsigned* gslots = (unsigned*)ws + 256 + sgrp * 64;

    const int tid  = threadIdx.x;
    const int wv   = tid >> 6;
    const int lane = tid & 63;
    const int qb   = lane >> 4;          // sample quad 0..3
    const int kc   = lane & 15;          // K interleave slot
    const int dcol = grp * 64 + dslc * 16 + wv;
    const int row0 = sgrp * 16;
    const int fcol0 = grp * 16 + dslc * 4;
    const int gid  = blkid * NTHR + tid;
    const int bfin = qb * 4 + kc;        // owned sample (valid when kc<4)

    // ---- P0 (identical to v6 PACKED) ----
    pack_gate(ws + OFF_P_EW0, eW0, Fsz, 7, gid);
    pack_gate(ws + OFF_P_EU0, eU0, Dsz, 9, gid);
    pack_wsum(ws + OFF_P_WSUM, eW1, eU1, gid);
    pack_wdeca_p(ws + OFF_P_WDECA, dU0, dW0, dw, gid);
    pack_gate(ws + OFF_P_DW0, dW0, Fsz, 7, gid);
    pack_gate(ws + OFF_P_DU0, dU0, Dsz, 9, gid);
    pack_gate(ws + OFF_P_DW1, dW1, Dsz, 9, gid);
    pack_gate(ws + OFF_P_DU1, dU1, Dsz, 9, gid);
    if (gid < ND) {
        float acc = db0[gid];
        for (int j = 0; j < Fsz; ++j) acc += db_[j] * dW0[(size_t)j * ND + gid];
        (ws + OFF_P_BF)[gid] = acc;
    }
    if (gid < Dsz * Fsz) {
        const int f = gid >> 9, k = gid & 511;
        (ws + OFF_P_DWT)[(size_t)f * Dsz + k] = dw[(size_t)k * Fsz + f];
    }
    gbar_all(fslots, blkid, 1);

    // resident dwT slice for this block's 4 fcols
    #pragma unroll
    for (int ii = 0; ii < 2; ++ii) {
        const int i = tid + ii * NTHR;
        DWL[i] = (ws + OFF_P_DWT)[(size_t)(fcol0 + (i >> 9)) * Dsz + (i & 511)];
    }
    __syncthreads();

    const float* pBF = ws + OFF_P_BF;
    const float4* W_EW0   = (const float4*)(ws + OFF_P_EW0)   + (size_t)dcol * 128;
    const float4* W_EU0   = (const float4*)(ws + OFF_P_EU0)   + (size_t)dcol * 512;
    const float4* W_WSUM  = (const float4*)(ws + OFF_P_WSUM)  + (size_t)dcol * 512;
    const float4* W_WDECA = (const float4*)(ws + OFF_P_WDECA) + (size_t)dcol * 512;
    const float4* W_DW0   = (const float4*)(ws + OFF_P_DW0)   + (size_t)dcol * 128;
    const float4* W_DU0   = (const float4*)(ws + OFF_P_DU0)   + (size_t)dcol * 512;
    const float4* W_DW1   = (const float4*)(ws + OFF_P_DW1)   + (size_t)dcol * 512;
    const float4* W_DU1   = (const float4*)(ws + OFF_P_DU1)   + (size_t)dcol * 512;

    unsigned ep = 0;
    int cur = 0;
    float c_car = 0.f, c_mid = 0.f;
    const float4 Z4 = make_float4(0.f, 0.f, 0.f, 0.f);

    // ======================= encoder =======================
    for (int t = 0; t < Tsz; ++t) {
        // ---- L0: prestage x + x-part BEFORE waiting for h_{t-1} ----
        stageX(XL2, enc_in + (size_t)t * Fsz, row0, 512);
        __syncthreads();
        float4 A0 = Z4, A1 = Z4, A2 = Z4, A3 = Z4;
        consT<8>(W_EW0, XL2, 512, kc, qb, A0, A1, A2, A3);
        wait_grp(gslots, ep);
        stageH(XL2, HT[cur], row0, 0);
        __syncthreads();
        consT<32>(W_EU0, XL2, 0, kc, qb, A0, A1, A2, A3);
        red16(A0); red16(A1); red16(A2); red16(A3);
        if (kc < 4) {
            float4 z = (kc == 0) ? A0 : (kc == 1) ? A1 : (kc == 2) ? A2 : A3;
            float cn; float h2 = fin4b(z, eb0, dcol, c_car, cn); c_mid = cn;
            st_coh(&HMT[(size_t)dcol * Bsz + row0 + bfin], h2);
        }
        arrive(&gslots[gm], ++ep);

        // ---- L1: h1 @ (eW1+eU1) ----
        wait_grp(gslots, ep);
        stageH(XL2, HMT, row0, 0);
        __syncthreads();
        A0 = Z4; A1 = Z4; A2 = Z4; A3 = Z4;
        consT<32>(W_WSUM, XL2, 0, kc, qb, A0, A1, A2, A3);
        red16(A0); red16(A1); red16(A2); red16(A3);
        if (kc < 4) {
            float4 z = (kc == 0) ? A0 : (kc == 1) ? A1 : (kc == 2) ? A2 : A3;
            float cn; float h2 = fin4b(z, eb1, dcol, c_mid, cn); c_car = cn;
            st_coh(&HT[cur ^ 1][(size_t)dcol * Bsz + row0 + bfin], h2);
        }
        arrive(&gslots[gm], ++ep);
        cur ^= 1;
    }

    // ======================= decoder t=0 =======================
    {
        stageX(XL2, dec_in, row0, 512);
        __syncthreads();
        float4 A0 = Z4, A1 = Z4, A2 = Z4, A3 = Z4;
        consT<8>(W_DW0, XL2, 512, kc, qb, A0, A1, A2, A3);
        wait_grp(gslots, ep);
        stageH(XL2, HT[cur], row0, 0);
        __syncthreads();
        consT<32>(W_DU0, XL2, 0, kc, qb, A0, A1, A2, A3);
        red16(A0); red16(A1); red16(A2); red16(A3);
        if (kc < 4) {
            float4 z = (kc == 0) ? A0 : (kc == 1) ? A1 : (kc == 2) ? A2 : A3;
            float cn; float h2 = fin4b(z, db0, dcol, c_car, cn);   // c discarded
            st_coh(&HMT[(size_t)dcol * Bsz + row0 + bfin], h2);
        }
        arrive(&gslots[gm], ++ep);
        // L1: hA@dW1 + h_old@dU1 (rows 0..511 still hold HT[cur]); old carry
        wait_grp(gslots, ep);
        stageH(XL2, HMT, row0, 512);
        __syncthreads();
        A0 = Z4; A1 = Z4; A2 = Z4; A3 = Z4;
        consT<32>(W_DU1, XL2, 0,   kc, qb, A0, A1, A2, A3);
        consT<32>(W_DW1, XL2, 512, kc, qb, A0, A1, A2, A3);
        red16(A0); red16(A1); red16(A2); red16(A3);
        if (kc < 4) {
            float4 z = (kc == 0) ? A0 : (kc == 1) ? A1 : (kc == 2) ? A2 : A3;
            float cn; float h2 = fin4b(z, db1, dcol, c_car, cn); c_car = cn;
            st_coh(&HT[cur ^ 1][(size_t)dcol * Bsz + row0 + bfin], h2);
        }
        arrive(&gslots[gm], ++ep);
        cur ^= 1;
    }

    // ======================= decoder t=1..127 =======================
    for (int t = 1; t < Tsz; ++t) {
        const int tt = Tsz - t;
        // ---- L0 folded (h @ WDECA + bfold) + fused out partials ----
        wait_grp(gslots, ep);
        stageH(XL2, HT[cur], row0, 0);
        __syncthreads();
        float4 A0 = Z4, A1 = Z4, A2 = Z4, A3 = Z4;
        consT<32>(W_WDECA, XL2, 0, kc, qb, A0, A1, A2, A3);
        out_part_n(XL2, DWL, ORED, kc, qb, wv);
        red16(A0); red16(A1); red16(A2); red16(A3);
        if (kc < 4) {
            float4 z = (kc == 0) ? A0 : (kc == 1) ? A1 : (kc == 2) ? A2 : A3;
            float cn; float h2 = fin4b(z, pBF, dcol, c_car, cn);   // c discarded
            st_coh(&HMT[(size_t)dcol * Bsz + row0 + bfin], h2);
        }
        arrive(&gslots[gm], ++ep);
        if (tid < 64) {        // out row emit off the critical path
            const int bb = tid >> 2, ff = tid & 3;
            const int fc = fcol0 + ff;
            const float* r = ORED + bb * 16 + ff * 4;
            float s = r[0] + r[1] + r[2] + r[3] + db_[fc];
            out[((size_t)(row0 + bb) * Tsz + tt) * Fsz + fc] = s;
        }
        // ---- L1: hA@dW1 + h@dU1 (h rows 0..511 reused from LDS) ----
        wait_grp(gslots, ep);
        stageH(XL2, HMT, row0, 512);
        __syncthreads();
        A0 = Z4; A1 = Z4; A2 = Z4; A3 = Z4;
        consT<32>(W_DU1, XL2, 0,   kc, qb, A0, A1, A2, A3);
        consT<32>(W_DW1, XL2, 512, kc, qb, A0, A1, A2, A3);
        red16(A0); red16(A1); red16(A2); red16(A3);
        if (kc < 4) {
            float4 z = (kc == 0) ? A0 : (kc == 1) ? A1 : (kc == 2) ? A2 : A3;
            float cn; float h2 = fin4b(z, db1, dcol, c_car, cn); c_car = cn;
            st_coh(&HT[cur ^ 1][(size_t)dcol * Bsz + row0 + bfin], h2);
        }
        arrive(&gslots[gm], ++ep);
        cur ^= 1;
    }

    // ======================= final out_127 -> row 0 =======================
    wait_grp(gslots, ep);
    stageH(XL2, HT[cur], row0, 0);
    __syncthreads();
    out_part_n(XL2, DWL, ORED, kc, qb, wv);
    __syncthreads();
    if (tid < 64) {
        const int bb = tid >> 2, ff = tid & 3;
        const int fc = fcol0 + ff;
        const float* r = ORED + bb * 16 + ff * 4;
        float s = r[0] + r[1] + r[2] + r[3] + db_[fc];
        out[((size_t)(row0 + bb) * Tsz + 0) * Fsz + fc] = s;
    }
}

// =====================================================================
// ======================  v6 fallback kernel  =========================
// =====================================================================

__device__ __forceinline__ void stage_vec(float* XL, int xstr, int dstoff,
        const float* src, int row0, int ld, int klen, int c4shift) {
    const int q = klen >> 2;
    const int n4 = q * 16;
    for (int i = threadIdx.x; i < n4; i += NTHR) {
        const int row = i >> c4shift;
        const int c4 = i & (q - 1);
        float4 v = *(const float4*)(src + (size_t)(row0 + row) * ld + (c4 << 2));
        *(float4*)(XL + row * xstr + dstoff + (c4 << 2)) = v;
    }
}
__device__ __forceinline__ void stage_coh_T(float* XL, int xstr, int dstoff,
        const float* HTsrc, int row0) {
    for (int i = threadIdx.x; i < Dsz * 16; i += NTHR) {
        const int d = i >> 4;
        const int bb = i & 15;
        XL[bb * xstr + dstoff + d] = ld_coh(HTsrc + (size_t)d * Bsz + row0 + bb);
    }
}
__device__ __forceinline__ void acc_segS(float4& z, const float* xp,
                                         const float* W, int kbase, int ksub, int dcol) {
    for (int j = 0; j < ksub; ++j) {
        const float x = xp[j];
        const float* wr = W + (size_t)(kbase + j) * ND + dcol;
        z.x += x * wr[0];
        z.y += x * wr[Dsz];
        z.z += x * wr[2 * Dsz];
        z.w += x * wr[3 * Dsz];
    }
}
__device__ __forceinline__ void reduce4(float4& z) {
    z.x += __shfl_xor(z.x, 16); z.x += __shfl_xor(z.x, 32);
    z.y += __shfl_xor(z.y, 16); z.y += __shfl_xor(z.y, 32);
    z.z += __shfl_xor(z.z, 16); z.z += __shfl_xor(z.z, 32);
    z.w += __shfl_xor(z.w, 16); z.w += __shfl_xor(z.w, 32);
}
__device__ __forceinline__ float lstm_fin(float4 z, const float* bias, int dcol,
                                          float cprev, float& c2out) {
    float gi = sigf(z.x + bias[dcol]);
    float gf = sigf(z.y + bias[Dsz + dcol]);
    float gg = fmaxf(z.z + bias[2 * Dsz + dcol], 0.f);
    float go = sigf(z.w + bias[3 * Dsz + dcol]);
    float c2 = gf * cprev + gi * gg;
    c2out = c2;
    return go * fmaxf(c2, 0.f);
}
__device__ __forceinline__ void out_part(const float* XL, int xstr, float* ORED,
                                         int b, int kc, int w, int fcol,
                                         const float* dwT) {
    const int q = w >> 2;
    const float* xp = XL + b * xstr + q * 128 + kc * 32;
    const float* wt = dwT + (size_t)fcol * Dsz + q * 128 + kc * 32;
    float acc = 0.f;
    #pragma unroll
    for (int j = 0; j < 32; j += 4) {
        float4 x4 = *(const float4*)(xp + j);
        float4 w4 = *(const float4*)(wt + j);
        acc += x4.x * w4.x + x4.y * w4.y + x4.z * w4.z + x4.w * w4.w;
    }
    acc += __shfl_xor(acc, 16); acc += __shfl_xor(acc, 32);
    if ((threadIdx.x & 63) < 16) ORED[b * 16 + (w & 3) * 4 + q] = acc;
}

__global__ void __launch_bounds__(NTHR, 1)
lstm_ae_fb(const float* enc_in, const float* dec_in,
           const float* eW0, const float* eU0, const float* eb0,
           const float* eW1, const float* eU1, const float* eb1,
           const float* dW0, const float* dU0, const float* db0,
           const float* dW1, const float* dU1, const float* db1,
           const float* dw, const float* db_, float* out, float* ws)
{
    __shared__ float XL[16 * 1028];
    __shared__ float ORED[256];

    unsigned* fslots = (unsigned*)ws;
    float* HT[2] = { ws + OFF_HT0, ws + OFF_HT1 };
    float* HMT = ws + OFF_HMT;

    const int blkid = blockIdx.x;
    const int grp  = blkid & 7;
    const int mem  = blkid >> 3;
    const int sgrp = mem & 7;
    const int dslc = mem >> 3;
    const int gm   = dslc * 8 + grp;
    unsigned* gslots = (unsigned*)ws + 256 + sgrp * 64;

    const int tid  = threadIdx.x;
    const int w    = tid >> 6;
    const int lane = tid & 63;
    const int b    = lane & 15;
    const int kc   = lane >> 4;
    const int dcol = grp * 64 + dslc * 16 + w;
    const int bgl  = sgrp * 16 + b;
    const int row0 = sgrp * 16;
    const int fcol = grp * 16 + dslc * 4 + (w & 3);
    const int gid  = blkid * NTHR + tid;

    pack_wsum(ws + OFF_F_WSUM, eW1, eU1, gid);
    pack_wdeca_p(ws + OFF_F_WDECA, dU0, dW0, dw, gid);
    if (gid < ND) {
        float acc = db0[gid];
        for (int j = 0; j < Fsz; ++j) acc += db_[j] * dW0[(size_t)j * ND + gid];
        (ws + OFF_F_BF)[gid] = acc;
    }
    if (gid < Dsz * Fsz) {
        const int f = gid >> 9, k = gid & 511;
        (ws + OFF_F_DWT)[(size_t)f * Dsz + k] = dw[(size_t)k * Fsz + f];
    }
    const float* pWSUM = ws + OFF_F_WSUM;
    const float* pWDECA = ws + OFF_F_WDECA;
    const float* pBF = ws + OFF_F_BF;
    const float* pDWT = ws + OFF_F_DWT;
    gbar_all(fslots, blkid, 1);

    unsigned ep = 0;
    int cur = 0;
    float c_car = 0.f;

    for (int t = 0; t < Tsz; ++t) {
        stage_vec(XL, 644, 0, enc_in + (size_t)t * Fsz, row0, Tsz * Fsz, 128, 5);
        __syncthreads();
        float4 z = make_float4(0.f, 0.f, 0.f, 0.f);
        acc_segS(z, XL + b * 644 + kc * 32, eW0, kc * 32, 32, dcol);
        wait_grp(gslots, ep);
        stage_coh_T(XL, 644, 128, HT[cur], row0);
        __syncthreads();
        acc_segS(z, XL + b * 644 + 128 + kc * 128, eU0, kc * 128, 128, dcol);
        reduce4(z);
        float c1 = 0.f;
        if (lane < 16) {
            float h2 = lstm_fin(z, eb0, dcol, c_car, c1);
            st_coh(&HMT[(size_t)dcol * Bsz + bgl], h2);
        }
        arrive(&gslots[gm], ++ep);
        wait_grp(gslots, ep);
        stage_coh_T(XL, 516, 0, HMT, row0);
        __syncthreads();
        z = make_float4(0.f, 0.f, 0.f, 0.f);
        {
            const float4* wp = (const float4*)pWSUM + (size_t)dcol * 512 + kc * 128;
            const float* xp = XL + b * 516 + kc * 128;
            #pragma unroll 4
            for (int j = 0; j < 128; j += 4) {
                float4 x4 = *(const float4*)(xp + j);
                float4 w0 = wp[j], w1 = wp[j + 1], w2 = wp[j + 2], w3 = wp[j + 3];
                z.x += x4.x*w0.x + x4.y*w1.x + x4.z*w2.x + x4.w*w3.x;
                z.y += x4.x*w0.y + x4.y*w1.y + x4.z*w2.y + x4.w*w3.y;
                z.z += x4.x*w0.z + x4.y*w1.z + x4.z*w2.z + x4.w*w3.z;
                z.w += x4.x*w0.w + x4.y*w1.w + x4.z*w2.w + x4.w*w3.w;
            }
        }
        reduce4(z);
        if (lane < 16) {
            float c2;
            float h2 = lstm_fin(z, eb1, dcol, c1, c2);
            c_car = c2;
            st_coh(&HT[cur ^ 1][(size_t)dcol * Bsz + bgl], h2);
        }
        arrive(&gslots[gm], ++ep);
        cur ^= 1;
    }

    stage_vec(XL, 644, 0, dec_in, row0, Tsz * Fsz, 128, 5);
    __syncthreads();
    {
        float4 z = make_float4(0.f, 0.f, 0.f, 0.f);
        acc_segS(z, XL + b * 644 + kc * 32, dW0, kc * 32, 32, dcol);
        wait_grp(gslots, ep);
        stage_coh_T(XL, 644, 128, HT[cur], row0);
        __syncthreads();
        acc_segS(z, XL + b * 644 + 128 + kc * 128, dU0, kc * 128, 128, dcol);
        reduce4(z);
        if (lane < 16) {
            float cd;
            float h2 = lstm_fin(z, db0, dcol, c_car, cd);
            st_coh(&HMT[(size_t)dcol * Bsz + bgl], h2);
        }
        arrive(&gslots[gm], ++ep);
    }
    wait_grp(gslots, ep);
    stage_coh_T(XL, 1028, 0, HT[cur], row0);
    stage_coh_T(XL, 1028, 512, HMT, row0);
    __syncthreads();
    {
        float4 z = make_float4(0.f, 0.f, 0.f, 0.f);
        acc_segS(z, XL + b * 1028 + kc * 128, dU1, kc * 128, 128, dcol);
        acc_segS(z, XL + b * 1028 + 512 + kc * 128, dW1, kc * 128, 128, dcol);
        reduce4(z);
        if (lane < 16) {
            float c2;
            float h2 = lstm_fin(z, db1, dcol, c_car, c2);
            c_car = c2;
            st_coh(&HT[cur ^ 1][(size_t)dcol * Bsz + bgl], h2);
        }
    }
    arrive(&gslots[gm], ++ep);
    cur ^= 1;

    for (int t = 1; t < Tsz; ++t) {
        const int tt = Tsz - t;
        wait_grp(gslots, ep);
        stage_coh_T(XL, 1028, 0, HT[cur], row0);
        __syncthreads();
        {
            float4 z = make_float4(0.f, 0.f, 0.f, 0.f);
            const float4* wp = (const float4*)pWDECA + (size_t)dcol * 512 + kc * 128;
            const float* xp = XL + b * 1028 + kc * 128;
            #pragma unroll 4
            for (int j = 0; j < 128; j += 4) {
                float4 x4 = *(const float4*)(xp + j);
                float4 w0 = wp[j], w1 = wp[j + 1], w2 = wp[j + 2], w3 = wp[j + 3];
                z.x += x4.x*w0.x + x4.y*w1.x + x4.z*w2.x + x4.w*w3.x;
                z.y += x4.x*w0.y + x4.y*w1.y + x4.z*w2.y + x4.w*w3.y;
                z.z += x4.x*w0.z + x4.y*w1.z + x4.z*w2.z + x4.w*w3.z;
                z.w += x4.x*w0.w + x4.y*w1.w + x4.z*w2.w + x4.w*w3.w;
            }
            reduce4(z);
            out_part(XL, 1028, ORED, b, kc, w, fcol, pDWT);
            if (lane < 16) {
                float cd;
                float h2 = lstm_fin(z, pBF, dcol, c_car, cd);
                st_coh(&HMT[(size_t)dcol * Bsz + bgl], h2);
            }
        }
        arrive(&gslots[gm], ++ep);
        if (tid < 64) {
            const int bb = tid >> 2, ff = tid & 3;
            const int fc = grp * 16 + dslc * 4 + ff;
            const float* r = ORED + bb * 16 + ff * 4;
            float s = r[0] + r[1] + r[2] + r[3] + db_[fc];
            out[((size_t)(row0 + bb) * Tsz + tt) * Fsz + fc] = s;
        }
        wait_grp(gslots, ep);
        stage_coh_T(XL, 1028, 512, HMT, row0);
        __syncthreads();
        {
            float4 z = make_float4(0.f, 0.f, 0.f, 0.f);
            acc_segS(z, XL + b * 1028 + kc * 128, dU1, kc * 128, 128, dcol);
            acc_segS(z, XL + b * 1028 + 512 + kc * 128, dW1, kc * 128, 128, dcol);
            reduce4(z);
            if (lane < 16) {
                float c2;
                float h2 = lstm_fin(z, db1, dcol, c_car, c2);
                c_car = c2;
                st_coh(&HT[cur ^ 1][(size_t)dcol * Bsz + bgl], h2);
            }
        }
        arrive(&gslots[gm], ++ep);
        cur ^= 1;
    }

    wait_grp(gslots, ep);
    stage_coh_T(XL, 516, 0, HT[cur], row0);
    __syncthreads();
    out_part(XL, 516, ORED, b, kc, w, fcol, pDWT);
    __syncthreads();
    if (tid < 64) {
        const int bb = tid >> 2, ff = tid & 3;
        const int fc = grp * 16 + dslc * 4 + ff;
        const float* r = ORED + bb * 16 + ff * 4;
        float s = r[0] + r[1] + r[2] + r[3] + db_[fc];
        out[((size_t)(row0 + bb) * Tsz + 0) * Fsz + fc] = s;
    }
}

extern "C" void kernel_launch(void* const* d_in, const int* in_sizes, int n_in,
                              void* d_out, int out_size, void* d_ws, size_t ws_size,
                              hipStream_t stream) {
    (void)in_sizes; (void)n_in; (void)out_size;
    const float* enc_in = (const float*)d_in[0];
    const float* dec_in = (const float*)d_in[1];
    const float* eW0 = (const float*)d_in[2];
    const float* eU0 = (const float*)d_in[3];
    const float* eb0 = (const float*)d_in[4];
    const float* eW1 = (const float*)d_in[5];
    const float* eU1 = (const float*)d_in[6];
    const float* eb1 = (const float*)d_in[7];
    const float* dW0 = (const float*)d_in[8];
    const float* dU0 = (const float*)d_in[9];
    const float* db0 = (const float*)d_in[10];
    const float* dW1 = (const float*)d_in[11];
    const float* dU1 = (const float*)d_in[12];
    const float* db1 = (const float*)d_in[13];
    const float* dw  = (const float*)d_in[14];
    const float* db_ = (const float*)d_in[15];
    float* out = (float*)d_out;
    float* ws = (float*)d_ws;

    // zero: all barrier slots + HT0 (initial h = 0)
    hipMemsetAsync(d_ws, 0, (size_t)(OFF_HT0 + Dsz * Bsz) * sizeof(float), stream);

    if (ws_size >= (size_t)WS_PACKED_FLOATS * sizeof(float))
        lstm_ae_v8<<<NBLK, NTHR, 0, stream>>>(
            enc_in, dec_in, eW0, eU0, eb0, eW1, eU1, eb1,
            dW0, dU0, db0, dW1, dU1, db1, dw, db_, out, ws);
    else
        lstm_ae_fb<<<NBLK, NTHR, 0, stream>>>(
            enc_in, dec_in, eW0, eU0, eb0, eW1, eU1, eb1,
            dW0, dU0, db0, dW1, dU1, db1, dw, db_, out, ws);
}

// Round 3
// 10269.940 us; speedup vs baseline: 6.2745x; 1.1758x over previous
//
#include <hip/hip_runtime.h>

// =====================================================================
// LSTM autoencoder v9: dual-chain software pipelining to hide the
// inter-block hop. Each block's 16 samples split into two independent
// 8-sample chains (A,B) with separate barrier epochs; phase order
// A-L0, B-L0, A-L1, B-L1 so each chain's barrier+h-exchange latency is
// hidden under the other chain's compute. Lane layout (kh,qb2,kc):
// 2-way K-split x 2 sample-quads x 16 kc; per-thread 4 samples x 4
// gates (FMA16), packed gate-interleaved weights as v8, reduce =
// xor{1,2,4,8,32}. LDS: two 48KB x/h buffers (row stride 12 floats,
// conflict-free, no swizzle needed). v8 fallback kernel retained.
// =====================================================================

#define Bsz 128
#define Tsz 128
#define Fsz 128
#define Dsz 512
#define ND  2048
#define NBLK 256
#define NTHR 1024

// ---- ws layout (float offsets) ----
#define OFF_HT0  1024
#define OFF_HT1  (OFF_HT0 + Dsz*Bsz)
#define OFF_HMT  (OFF_HT1 + Dsz*Bsz)
#define OFF_WEND (OFF_HMT + Dsz*Bsz)
// packed weights (gate-interleaved float4: Wp4[dcol*K + k] = {i,f,g,o})
#define OFF_P_EW0   OFF_WEND
#define OFF_P_EU0   (OFF_P_EW0 + Fsz*ND)
#define OFF_P_WSUM  (OFF_P_EU0 + Dsz*ND)
#define OFF_P_WDECA (OFF_P_WSUM + Dsz*ND)
#define OFF_P_DW0   (OFF_P_WDECA + Dsz*ND)
#define OFF_P_DU0   (OFF_P_DW0 + Fsz*ND)
#define OFF_P_DW1   (OFF_P_DU0 + Dsz*ND)
#define OFF_P_DU1   (OFF_P_DW1 + Dsz*ND)
#define OFF_P_BF    (OFF_P_DU1 + Dsz*ND)
#define OFF_P_DWT   (OFF_P_BF + ND)
#define WS_PACKED_FLOATS (OFF_P_DWT + Dsz*Fsz)
// fallback layout
#define OFF_F_WSUM  OFF_WEND
#define OFF_F_WDECA (OFF_F_WSUM + Dsz*ND)
#define OFF_F_BF    (OFF_F_WDECA + Dsz*ND)
#define OFF_F_DWT   (OFF_F_BF + ND)
#define WS_FALLBACK_FLOATS (OFF_F_DWT + Dsz*Fsz)

#define NR 12   // v9 LDS row stride: 8 data + 4 pad floats (16B aligned)

__device__ __forceinline__ float sigf(float x) {
    return 1.0f / (1.0f + __expf(-x));
}
__device__ __forceinline__ float ld_coh(const float* p) {
    return __hip_atomic_load((float*)p, __ATOMIC_RELAXED, __HIP_MEMORY_SCOPE_AGENT);
}
__device__ __forceinline__ void st_coh(float* p, float v) {
    __hip_atomic_store(p, v, __ATOMIC_RELAXED, __HIP_MEMORY_SCOPE_AGENT);
}

// ---- split group barrier (32 members, per-chain slot arrays) ----
__device__ __forceinline__ void arrive(unsigned* slot, unsigned ep) {
    __syncthreads();   // all waves' compute + coherent stores drained
    if (threadIdx.x == 0)
        __hip_atomic_store(slot, ep, __ATOMIC_RELEASE, __HIP_MEMORY_SCOPE_AGENT);
}
__device__ __forceinline__ void wait_grp(unsigned* gslots, unsigned ep) {
    if (threadIdx.x < 64) {
        for (;;) {
            unsigned v = (threadIdx.x < 32)
                ? __hip_atomic_load(&gslots[threadIdx.x], __ATOMIC_RELAXED,
                                    __HIP_MEMORY_SCOPE_AGENT)
                : ep;
            if (__all(v >= ep)) break;
            __builtin_amdgcn_s_sleep(1);
        }
    }
    __syncthreads();
}
__device__ __forceinline__ void gbar_all(unsigned* slots, int blkid, unsigned ep) {
    __syncthreads();
    if (threadIdx.x == 0) {
        __threadfence();
        __hip_atomic_store(&slots[blkid], ep, __ATOMIC_RELEASE,
                           __HIP_MEMORY_SCOPE_AGENT);
    }
    if (threadIdx.x < 64) {
        for (;;) {
            unsigned mn = ~0u;
            #pragma unroll
            for (int q = 0; q < 4; ++q) {
                unsigned v = __hip_atomic_load(&slots[threadIdx.x * 4 + q],
                                               __ATOMIC_RELAXED, __HIP_MEMORY_SCOPE_AGENT);
                mn = min(mn, v);
            }
            if (__all(mn >= ep)) break;
            __builtin_amdgcn_s_sleep(1);
        }
        if (threadIdx.x == 0) __threadfence();
    }
    __syncthreads();
}

// ---- P0 packing (identical to v6/v8) ----
__device__ void pack_gate(float* dst, const float* src, int K, int kshift, int gid) {
    const int total = K * Dsz;
    for (int u = gid; u < total; u += NBLK * NTHR) {
        const int dd = u >> kshift;
        const int k = u & (K - 1);
        const float* sp = src + (size_t)k * ND + dd;
        ((float4*)dst)[u] = make_float4(sp[0], sp[Dsz], sp[2 * Dsz], sp[3 * Dsz]);
    }
}
__device__ void pack_wsum(float* dst, const float* a, const float* bsrc, int gid) {
    for (int u = gid; u < Dsz * Dsz; u += NBLK * NTHR) {
        const int dd = u >> 9, k = u & 511;
        const float* pa = a + (size_t)k * ND + dd;
        const float* pb = bsrc + (size_t)k * ND + dd;
        ((float4*)dst)[u] = make_float4(pa[0] + pb[0], pa[Dsz] + pb[Dsz],
                                        pa[2*Dsz] + pb[2*Dsz], pa[3*Dsz] + pb[3*Dsz]);
    }
}
__device__ void pack_wdeca_p(float* dst, const float* dU0, const float* dW0,
                             const float* dw, int gid) {
    for (int u = gid; u < Dsz * Dsz; u += NBLK * NTHR) {
        const int dd = u >> 9, k = u & 511;
        const float* pu = dU0 + (size_t)k * ND + dd;
        float a0 = pu[0], a1 = pu[Dsz], a2 = pu[2*Dsz], a3 = pu[3*Dsz];
        const float* dwr = dw + k * Fsz;
        for (int j = 0; j < Fsz; ++j) {
            const float wv = dwr[j];
            const float* dr = dW0 + (size_t)j * ND + dd;
            a0 += wv * dr[0]; a1 += wv * dr[Dsz];
            a2 += wv * dr[2*Dsz]; a3 += wv * dr[3*Dsz];
        }
        ((float4*)dst)[u] = make_float4(a0, a1, a2, a3);
    }
}

// =====================================================================
// ======================  v9 kernel  ==================================
// =====================================================================

// stage 512 h rows (8 samples) from transposed coherent buffer
__device__ __forceinline__ void stageH9(float* XL, const float* HTsrc, int sr, int rbase) {
    #pragma unroll
    for (int ii = 0; ii < 4; ++ii) {
        const int i = (int)threadIdx.x + ii * NTHR;
        const int r = i >> 3, bb = i & 7;
        XL[(rbase + r) * NR + bb] = ld_coh(HTsrc + (size_t)r * Bsz + sr + bb);
    }
}
// stage 128 x rows (8 samples), 1 elem/thread
__device__ __forceinline__ void stageX9(float* XL, const float* src, int sr, int rbase) {
    const int r = (int)threadIdx.x & 127, bb = (int)threadIdx.x >> 7;
    XL[(rbase + r) * NR + bb] = src[(size_t)(sr + bb) * (Tsz * Fsz) + r];
}

#define FMA16(A0,A1,A2,A3,x4,w4) \
    A0.x += x4.x*w4.x; A0.y += x4.x*w4.y; A0.z += x4.x*w4.z; A0.w += x4.x*w4.w; \
    A1.x += x4.y*w4.x; A1.y += x4.y*w4.y; A1.z += x4.y*w4.z; A1.w += x4.y*w4.w; \
    A2.x += x4.z*w4.x; A2.y += x4.z*w4.y; A2.z += x4.z*w4.z; A2.w += x4.z*w4.w; \
    A3.x += x4.w*w4.x; A3.y += x4.w*w4.y; A3.z += x4.w*w4.z; A3.w += x4.w*w4.w;

// consume NJ*32 K-rows: Wp pre-offset by koff; Xb pre-offset by
// (rowbase+koff)*NR + qb2*4. Row step per j = 32.
template<int NJ>
__device__ __forceinline__ void consTv(const float4* __restrict__ Wp,
        const float* __restrict__ Xb,
        float4& A0, float4& A1, float4& A2, float4& A3)
{
    #pragma unroll 8
    for (int j = 0; j < NJ; ++j) {
        const float4 x4 = *(const float4*)(Xb + j * (32 * NR));
        const float4 w4 = Wp[j * 32];
        FMA16(A0, A1, A2, A3, x4, w4)
    }
}

// reduce over kc (bits 0..3) and kh (bit 5); bit 4 (qb2) NOT reduced
__device__ __forceinline__ void red32(float4& a) {
    #pragma unroll
    for (int m = 1; m <= 8; m <<= 1) {
        a.x += __shfl_xor(a.x, m);
        a.y += __shfl_xor(a.y, m);
        a.z += __shfl_xor(a.z, m);
        a.w += __shfl_xor(a.w, m);
    }
    a.x += __shfl_xor(a.x, 32);
    a.y += __shfl_xor(a.y, 32);
    a.z += __shfl_xor(a.z, 32);
    a.w += __shfl_xor(a.w, 32);
}
__device__ __forceinline__ float fin4b(float4 z, const float* bias, int dcol,
                                       float cprev, float& c2o) {
    float gi = sigf(z.x + bias[dcol]);
    float gf = sigf(z.y + bias[Dsz + dcol]);
    float gg = fmaxf(z.z + bias[2 * Dsz + dcol], 0.f);
    float go = sigf(z.w + bias[3 * Dsz + dcol]);
    float c2 = gf * cprev + gi * gg;
    c2o = c2;
    return go * fmaxf(c2, 0.f);
}

// fused dense-row partials for one chain: ORED[sample][ff*4+qk]
__device__ __forceinline__ void out_part9(const float* XL, const float* DWL, float* ORED,
                                          int xo, int koff, int wv)
{
    const int ff = wv & 3, qk = wv >> 2;
    float o0 = 0.f, o1 = 0.f, o2 = 0.f, o3 = 0.f;
    const float* Xb = XL + qk * 128 * NR + xo;
    const float* Wb = DWL + ff * 512 + qk * 128 + koff;
    #pragma unroll
    for (int j = 0; j < 4; ++j) {
        const float4 x4 = *(const float4*)(Xb + j * (32 * NR));
        const float w = Wb[j * 32];
        o0 += x4.x * w; o1 += x4.y * w; o2 += x4.z * w; o3 += x4.w * w;
    }
    #pragma unroll
    for (int m = 1; m <= 8; m <<= 1) {
        o0 += __shfl_xor(o0, m); o1 += __shfl_xor(o1, m);
        o2 += __shfl_xor(o2, m); o3 += __shfl_xor(o3, m);
    }
    o0 += __shfl_xor(o0, 32); o1 += __shfl_xor(o1, 32);
    o2 += __shfl_xor(o2, 32); o3 += __shfl_xor(o3, 32);
    const int lane = (int)threadIdx.x & 63;
    if ((lane & 47) == 0) {                 // kh==0 && kc==0 -> lanes 0,16
        const int q = (lane >> 4) & 1;      // qb2
        ORED[(q * 4 + 0) * 16 + ff * 4 + qk] = o0;
        ORED[(q * 4 + 1) * 16 + ff * 4 + qk] = o1;
        ORED[(q * 4 + 2) * 16 + ff * 4 + qk] = o2;
        ORED[(q * 4 + 3) * 16 + ff * 4 + qk] = o3;
    }
}

__global__ void __launch_bounds__(NTHR, 1)
lstm_ae_v9(const float* enc_in, const float* dec_in,
           const float* eW0, const float* eU0, const float* eb0,
           const float* eW1, const float* eU1, const float* eb1,
           const float* dW0, const float* dU0, const float* db0,
           const float* dW1, const float* dU1, const float* db1,
           const float* dw, const float* db_, float* out, float* ws)
{
    __shared__ float XLA[1024 * NR];   // 48 KB chain A: h rows 0..511, x/hA rows 512+
    __shared__ float XLB[1024 * NR];   // 48 KB chain B
    __shared__ float DWL[4 * 512];     //  8 KB resident dwT slice (4 fcols)
    __shared__ float OREDA[128];
    __shared__ float OREDB[128];

    unsigned* fslots = (unsigned*)ws;
    float* HT[2] = { ws + OFF_HT0, ws + OFF_HT1 };
    float* HMT = ws + OFF_HMT;

    const int blkid = blockIdx.x;
    const int grp  = blkid & 7;       // XCD / dcol-slice owner
    const int mem  = blkid >> 3;
    const int sgrp = mem & 7;
    const int dslc = mem >> 3;
    const int gm   = dslc * 8 + grp;  // member id (0..31)
    const int chA  = sgrp * 2, chB = chA + 1;     // 16 chains, 32 slots each
    unsigned* gsA = (unsigned*)ws + 256 + chA * 32;
    unsigned* gsB = (unsigned*)ws + 256 + chB * 32;
    const int srA = sgrp * 16;        // chain A samples [srA, srA+8)
    const int srB = sgrp * 16 + 8;

    const int tid  = threadIdx.x;
    const int wv   = tid >> 6;
    const int lane = tid & 63;
    const int kh   = lane >> 5;          // K-half bit
    const int qb2  = (lane >> 4) & 1;    // sample quad (of 2)
    const int kc   = lane & 15;          // K interleave slot
    const int koff = kh * 16 + kc;       // K offset within 32-row step
    const int dcol = grp * 64 + dslc * 16 + wv;
    const int fcol0 = grp * 16 + dslc * 4;
    const int gid  = blkid * NTHR + tid;
    const bool finw = (kh == 0) && (kc < 4);
    const int bfin = qb2 * 4 + kc;       // owned sample within chain (finw)
    const int xo   = koff * NR + qb2 * 4; // per-thread LDS read base

    // ---- P0 (identical to v8) ----
    pack_gate(ws + OFF_P_EW0, eW0, Fsz, 7, gid);
    pack_gate(ws + OFF_P_EU0, eU0, Dsz, 9, gid);
    pack_wsum(ws + OFF_P_WSUM, eW1, eU1, gid);
    pack_wdeca_p(ws + OFF_P_WDECA, dU0, dW0, dw, gid);
    pack_gate(ws + OFF_P_DW0, dW0, Fsz, 7, gid);
    pack_gate(ws + OFF_P_DU0, dU0, Dsz, 9, gid);
    pack_gate(ws + OFF_P_DW1, dW1, Dsz, 9, gid);
    pack_gate(ws + OFF_P_DU1, dU1, Dsz, 9, gid);
    if (gid < ND) {
        float acc = db0[gid];
        for (int j = 0; j < Fsz; ++j) acc += db_[j] * dW0[(size_t)j * ND + gid];
        (ws + OFF_P_BF)[gid] = acc;
    }
    if (gid < Dsz * Fsz) {
        const int f = gid >> 9, k = gid & 511;
        (ws + OFF_P_DWT)[(size_t)f * Dsz + k] = dw[(size_t)k * Fsz + f];
    }
    gbar_all(fslots, blkid, 1);

    // resident dwT slice for this block's 4 fcols
    #pragma unroll
    for (int ii = 0; ii < 2; ++ii) {
        const int i = tid + ii * NTHR;
        DWL[i] = (ws + OFF_P_DWT)[(size_t)(fcol0 + (i >> 9)) * Dsz + (i & 511)];
    }
    __syncthreads();

    const float* pBF = ws + OFF_P_BF;
    const float4* W_EW0   = (const float4*)(ws + OFF_P_EW0)   + (size_t)dcol * 128 + koff;
    const float4* W_EU0   = (const float4*)(ws + OFF_P_EU0)   + (size_t)dcol * 512 + koff;
    const float4* W_WSUM  = (const float4*)(ws + OFF_P_WSUM)  + (size_t)dcol * 512 + koff;
    const float4* W_WDECA = (const float4*)(ws + OFF_P_WDECA) + (size_t)dcol * 512 + koff;
    const float4* W_DW0   = (const float4*)(ws + OFF_P_DW0)   + (size_t)dcol * 128 + koff;
    const float4* W_DU0   = (const float4*)(ws + OFF_P_DU0)   + (size_t)dcol * 512 + koff;
    const float4* W_DW1   = (const float4*)(ws + OFF_P_DW1)   + (size_t)dcol * 512 + koff;
    const float4* W_DU1   = (const float4*)(ws + OFF_P_DU1)   + (size_t)dcol * 512 + koff;

    unsigned epA = 0, epB = 0;
    int cur = 0;
    float cA = 0.f, cmA = 0.f, cB = 0.f, cmB = 0.f;
    const float4 Z4 = make_float4(0.f, 0.f, 0.f, 0.f);

    // ======================= encoder =======================
    for (int t = 0; t < Tsz; ++t) {
        stageX9(XLA, enc_in + (size_t)t * Fsz, srA, 512);
        stageX9(XLB, enc_in + (size_t)t * Fsz, srB, 512);
        __syncthreads();
        // ---- A L0 ----
        {
            float4 A0 = Z4, A1 = Z4, A2 = Z4, A3 = Z4;
            consTv<4>(W_EW0, XLA + 512 * NR + xo, A0, A1, A2, A3);
            wait_grp(gsA, epA);
            stageH9(XLA, HT[cur], srA, 0);
            __syncthreads();
            consTv<16>(W_EU0, XLA + xo, A0, A1, A2, A3);
            red32(A0); red32(A1); red32(A2); red32(A3);
            if (finw) {
                float4 z = (kc == 0) ? A0 : (kc == 1) ? A1 : (kc == 2) ? A2 : A3;
                float cn; float h2 = fin4b(z, eb0, dcol, cA, cn); cmA = cn;
                st_coh(&HMT[(size_t)dcol * Bsz + srA + bfin], h2);
            }
            arrive(&gsA[gm], ++epA);
        }
        // ---- B L0 ----
        {
            float4 A0 = Z4, A1 = Z4, A2 = Z4, A3 = Z4;
            consTv<4>(W_EW0, XLB + 512 * NR + xo, A0, A1, A2, A3);
            wait_grp(gsB, epB);
            stageH9(XLB, HT[cur], srB, 0);
            __syncthreads();
            consTv<16>(W_EU0, XLB + xo, A0, A1, A2, A3);
            red32(A0); red32(A1); red32(A2); red32(A3);
            if (finw) {
                float4 z = (kc == 0) ? A0 : (kc == 1) ? A1 : (kc == 2) ? A2 : A3;
                float cn; float h2 = fin4b(z, eb0, dcol, cB, cn); cmB = cn;
                st_coh(&HMT[(size_t)dcol * Bsz + srB + bfin], h2);
            }
            arrive(&gsB[gm], ++epB);
        }
        // ---- A L1 ----
        {
            wait_grp(gsA, epA);
            stageH9(XLA, HMT, srA, 0);
            __syncthreads();
            float4 A0 = Z4, A1 = Z4, A2 = Z4, A3 = Z4;
            consTv<16>(W_WSUM, XLA + xo, A0, A1, A2, A3);
            red32(A0); red32(A1); red32(A2); red32(A3);
            if (finw) {
                float4 z = (kc == 0) ? A0 : (kc == 1) ? A1 : (kc == 2) ? A2 : A3;
                float cn; float h2 = fin4b(z, eb1, dcol, cmA, cn); cA = cn;
                st_coh(&HT[cur ^ 1][(size_t)dcol * Bsz + srA + bfin], h2);
            }
            arrive(&gsA[gm], ++epA);
        }
        // ---- B L1 ----
        {
            wait_grp(gsB, epB);
            stageH9(XLB, HMT, srB, 0);
            __syncthreads();
            float4 A0 = Z4, A1 = Z4, A2 = Z4, A3 = Z4;
            consTv<16>(W_WSUM, XLB + xo, A0, A1, A2, A3);
            red32(A0); red32(A1); red32(A2); red32(A3);
            if (finw) {
                float4 z = (kc == 0) ? A0 : (kc == 1) ? A1 : (kc == 2) ? A2 : A3;
                float cn; float h2 = fin4b(z, eb1, dcol, cmB, cn); cB = cn;
                st_coh(&HT[cur ^ 1][(size_t)dcol * Bsz + srB + bfin], h2);
            }
            arrive(&gsB[gm], ++epB);
        }
        cur ^= 1;
    }

    // ======================= decoder t=0 =======================
    {
        stageX9(XLA, dec_in, srA, 512);
        stageX9(XLB, dec_in, srB, 512);
        __syncthreads();
        // A L0 (c discarded)
        {
            float4 A0 = Z4, A1 = Z4, A2 = Z4, A3 = Z4;
            consTv<4>(W_DW0, XLA + 512 * NR + xo, A0, A1, A2, A3);
            wait_grp(gsA, epA);
            stageH9(XLA, HT[cur], srA, 0);
            __syncthreads();
            consTv<16>(W_DU0, XLA + xo, A0, A1, A2, A3);
            red32(A0); red32(A1); red32(A2); red32(A3);
            if (finw) {
                float4 z = (kc == 0) ? A0 : (kc == 1) ? A1 : (kc == 2) ? A2 : A3;
                float cd; float h2 = fin4b(z, db0, dcol, cA, cd);
                st_coh(&HMT[(size_t)dcol * Bsz + srA + bfin], h2);
            }
            arrive(&gsA[gm], ++epA);
        }
        // B L0
        {
            float4 A0 = Z4, A1 = Z4, A2 = Z4, A3 = Z4;
            consTv<4>(W_DW0, XLB + 512 * NR + xo, A0, A1, A2, A3);
            wait_grp(gsB, epB);
            stageH9(XLB, HT[cur], srB, 0);
            __syncthreads();
            consTv<16>(W_DU0, XLB + xo, A0, A1, A2, A3);
            red32(A0); red32(A1); red32(A2); red32(A3);
            if (finw) {
                float4 z = (kc == 0) ? A0 : (kc == 1) ? A1 : (kc == 2) ? A2 : A3;
                float cd; float h2 = fin4b(z, db0, dcol, cB, cd);
                st_coh(&HMT[(size_t)dcol * Bsz + srB + bfin], h2);
            }
            arrive(&gsB[gm], ++epB);
        }
        // A L1: h_old (rows 0..511, still staged) @ dU1 + hA (rows 512+) @ dW1; old carry
        {
            wait_grp(gsA, epA);
            stageH9(XLA, HMT, srA, 512);
            __syncthreads();
            float4 A0 = Z4, A1 = Z4, A2 = Z4, A3 = Z4;
            consTv<16>(W_DU1, XLA + xo, A0, A1, A2, A3);
            consTv<16>(W_DW1, XLA + 512 * NR + xo, A0, A1, A2, A3);
            red32(A0); red32(A1); red32(A2); red32(A3);
            if (finw) {
                float4 z = (kc == 0) ? A0 : (kc == 1) ? A1 : (kc == 2) ? A2 : A3;
                float cn; float h2 = fin4b(z, db1, dcol, cA, cn); cA = cn;
                st_coh(&HT[cur ^ 1][(size_t)dcol * Bsz + srA + bfin], h2);
            }
            arrive(&gsA[gm], ++epA);
        }
        // B L1
        {
            wait_grp(gsB, epB);
            stageH9(XLB, HMT, srB, 512);
            __syncthreads();
            float4 A0 = Z4, A1 = Z4, A2 = Z4, A3 = Z4;
            consTv<16>(W_DU1, XLB + xo, A0, A1, A2, A3);
            consTv<16>(W_DW1, XLB + 512 * NR + xo, A0, A1, A2, A3);
            red32(A0); red32(A1); red32(A2); red32(A3);
            if (finw) {
                float4 z = (kc == 0) ? A0 : (kc == 1) ? A1 : (kc == 2) ? A2 : A3;
                float cn; float h2 = fin4b(z, db1, dcol, cB, cn); cB = cn;
                st_coh(&HT[cur ^ 1][(size_t)dcol * Bsz + srB + bfin], h2);
            }
            arrive(&gsB[gm], ++epB);
        }
        cur ^= 1;
    }

    // ======================= decoder t=1..127 =======================
    for (int t = 1; t < Tsz; ++t) {
        const int tt = Tsz - t;
        // ---- A L0 folded + fused out partials ----
        {
            wait_grp(gsA, epA);
            stageH9(XLA, HT[cur], srA, 0);
            __syncthreads();
            float4 A0 = Z4, A1 = Z4, A2 = Z4, A3 = Z4;
            consTv<16>(W_WDECA, XLA + xo, A0, A1, A2, A3);
            out_part9(XLA, DWL, OREDA, xo, koff, wv);
            red32(A0); red32(A1); red32(A2); red32(A3);
            if (finw) {
                float4 z = (kc == 0) ? A0 : (kc == 1) ? A1 : (kc == 2) ? A2 : A3;
                float cd; float h2 = fin4b(z, pBF, dcol, cA, cd);
                st_coh(&HMT[(size_t)dcol * Bsz + srA + bfin], h2);
            }
            arrive(&gsA[gm], ++epA);
            if (tid < 32) {
                const int bb = tid >> 2, ff = tid & 3;
                const int fc = fcol0 + ff;
                const float* r = OREDA + bb * 16 + ff * 4;
                float s = r[0] + r[1] + r[2] + r[3] + db_[fc];
                out[((size_t)(srA + bb) * Tsz + tt) * Fsz + fc] = s;
            }
        }
        // ---- B L0 ----
        {
            wait_grp(gsB, epB);
            stageH9(XLB, HT[cur], srB, 0);
            __syncthreads();
            float4 A0 = Z4, A1 = Z4, A2 = Z4, A3 = Z4;
            consTv<16>(W_WDECA, XLB + xo, A0, A1, A2, A3);
            out_part9(XLB, DWL, OREDB, xo, koff, wv);
            red32(A0); red32(A1); red32(A2); red32(A3);
            if (finw) {
                float4 z = (kc == 0) ? A0 : (kc == 1) ? A1 : (kc == 2) ? A2 : A3;
                float cd; float h2 = fin4b(z, pBF, dcol, cB, cd);
                st_coh(&HMT[(size_t)dcol * Bsz + srB + bfin], h2);
            }
            arrive(&gsB[gm], ++epB);
            if (tid < 32) {
                const int bb = tid >> 2, ff = tid & 3;
                const int fc = fcol0 + ff;
                const float* r = OREDB + bb * 16 + ff * 4;
                float s = r[0] + r[1] + r[2] + r[3] + db_[fc];
                out[((size_t)(srB + bb) * Tsz + tt) * Fsz + fc] = s;
            }
        }
        // ---- A L1 ----
        {
            wait_grp(gsA, epA);
            stageH9(XLA, HMT, srA, 512);
            __syncthreads();
            float4 A0 = Z4, A1 = Z4, A2 = Z4, A3 = Z4;
            consTv<16>(W_DU1, XLA + xo, A0, A1, A2, A3);
            consTv<16>(W_DW1, XLA + 512 * NR + xo, A0, A1, A2, A3);
            red32(A0); red32(A1); red32(A2); red32(A3);
            if (finw) {
                float4 z = (kc == 0) ? A0 : (kc == 1) ? A1 : (kc == 2) ? A2 : A3;
                float cn; float h2 = fin4b(z, db1, dcol, cA, cn); cA = cn;
                st_coh(&HT[cur ^ 1][(size_t)dcol * Bsz + srA + bfin], h2);
            }
            arrive(&gsA[gm], ++epA);
        }
        // ---- B L1 ----
        {
            wait_grp(gsB, epB);
            stageH9(XLB, HMT, srB, 512);
            __syncthreads();
            float4 A0 = Z4, A1 = Z4, A2 = Z4, A3 = Z4;
            consTv<16>(W_DU1, XLB + xo, A0, A1, A2, A3);
            consTv<16>(W_DW1, XLB + 512 * NR + xo, A0, A1, A2, A3);
            red32(A0); red32(A1); red32(A2); red32(A3);
            if (finw) {
                float4 z = (kc == 0) ? A0 : (kc == 1) ? A1 : (kc == 2) ? A2 : A3;
                float cn; float h2 = fin4b(z, db1, dcol, cB, cn); cB = cn;
                st_coh(&HT[cur ^ 1][(size_t)dcol * Bsz + srB + bfin], h2);
            }
            arrive(&gsB[gm], ++epB);
        }
        cur ^= 1;
    }

    // ======================= final out_127 -> row 0 =======================
    wait_grp(gsA, epA);
    stageH9(XLA, HT[cur], srA, 0);
    __syncthreads();
    out_part9(XLA, DWL, OREDA, xo, koff, wv);
    wait_grp(gsB, epB);
    stageH9(XLB, HT[cur], srB, 0);
    __syncthreads();
    out_part9(XLB, DWL, OREDB, xo, koff, wv);
    __syncthreads();
    if (tid < 64) {
        const int half = tid >> 5;            // 0 = chain A, 1 = chain B
        const int l = tid & 31;
        const int bb = l >> 2, ff = l & 3;
        const int fc = fcol0 + ff;
        const float* ored = half ? OREDB : OREDA;
        const int sr = half ? srB : srA;
        const float* r = ored + bb * 16 + ff * 4;
        float s = r[0] + r[1] + r[2] + r[3] + db_[fc];
        out[((size_t)(sr + bb) * Tsz + 0) * Fsz + fc] = s;
    }
}

// =====================================================================
// ======================  v8 fallback kernel  =========================
// =====================================================================

__device__ __forceinline__ void stage_vec(float* XL, int xstr, int dstoff,
        const float* src, int row0, int ld, int klen, int c4shift) {
    const int q = klen >> 2;
    const int n4 = q * 16;
    for (int i = threadIdx.x; i < n4; i += NTHR) {
        const int row = i >> c4shift;
        const int c4 = i & (q - 1);
        float4 v = *(const float4*)(src + (size_t)(row0 + row) * ld + (c4 << 2));
        *(float4*)(XL + row * xstr + dstoff + (c4 << 2)) = v;
    }
}
__device__ __forceinline__ void stage_coh_T(float* XL, int xstr, int dstoff,
        const float* HTsrc, int row0) {
    for (int i = threadIdx.x; i < Dsz * 16; i += NTHR) {
        const int d = i >> 4;
        const int bb = i & 15;
        XL[bb * xstr + dstoff + d] = ld_coh(HTsrc + (size_t)d * Bsz + row0 + bb);
    }
}
__device__ __forceinline__ void acc_segS(float4& z, const float* xp,
                                         const float* W, int kbase, int ksub, int dcol) {
    for (int j = 0; j < ksub; ++j) {
        const float x = xp[j];
        const float* wr = W + (size_t)(kbase + j) * ND + dcol;
        z.x += x * wr[0];
        z.y += x * wr[Dsz];
        z.z += x * wr[2 * Dsz];
        z.w += x * wr[3 * Dsz];
    }
}
__device__ __forceinline__ void reduce4(float4& z) {
    z.x += __shfl_xor(z.x, 16); z.x += __shfl_xor(z.x, 32);
    z.y += __shfl_xor(z.y, 16); z.y += __shfl_xor(z.y, 32);
    z.z += __shfl_xor(z.z, 16); z.z += __shfl_xor(z.z, 32);
    z.w += __shfl_xor(z.w, 16); z.w += __shfl_xor(z.w, 32);
}
__device__ __forceinline__ float lstm_fin(float4 z, const float* bias, int dcol,
                                          float cprev, float& c2out) {
    float gi = sigf(z.x + bias[dcol]);
    float gf = sigf(z.y + bias[Dsz + dcol]);
    float gg = fmaxf(z.z + bias[2 * Dsz + dcol], 0.f);
    float go = sigf(z.w + bias[3 * Dsz + dcol]);
    float c2 = gf * cprev + gi * gg;
    c2out = c2;
    return go * fmaxf(c2, 0.f);
}
__device__ __forceinline__ void out_part(const float* XL, int xstr, float* ORED,
                                         int b, int kc, int w, int fcol,
                                         const float* dwT) {
    const int q = w >> 2;
    const float* xp = XL + b * xstr + q * 128 + kc * 32;
    const float* wt = dwT + (size_t)fcol * Dsz + q * 128 + kc * 32;
    float acc = 0.f;
    #pragma unroll
    for (int j = 0; j < 32; j += 4) {
        float4 x4 = *(const float4*)(xp + j);
        float4 w4 = *(const float4*)(wt + j);
        acc += x4.x * w4.x + x4.y * w4.y + x4.z * w4.z + x4.w * w4.w;
    }
    acc += __shfl_xor(acc, 16); acc += __shfl_xor(acc, 32);
    if ((threadIdx.x & 63) < 16) ORED[b * 16 + (w & 3) * 4 + q] = acc;
}

__global__ void __launch_bounds__(NTHR, 1)
lstm_ae_fb(const float* enc_in, const float* dec_in,
           const float* eW0, const float* eU0, const float* eb0,
           const float* eW1, const float* eU1, const float* eb1,
           const float* dW0, const float* dU0, const float* db0,
           const float* dW1, const float* dU1, const float* db1,
           const float* dw, const float* db_, float* out, float* ws)
{
    __shared__ float XL[16 * 1028];
    __shared__ float ORED[256];

    unsigned* fslots = (unsigned*)ws;
    float* HT[2] = { ws + OFF_HT0, ws + OFF_HT1 };
    float* HMT = ws + OFF_HMT;

    const int blkid = blockIdx.x;
    const int grp  = blkid & 7;
    const int mem  = blkid >> 3;
    const int sgrp = mem & 7;
    const int dslc = mem >> 3;
    const int gm   = dslc * 8 + grp;
    unsigned* gslots = (unsigned*)ws + 256 + sgrp * 64;

    const int tid  = threadIdx.x;
    const int w    = tid >> 6;
    const int lane = tid & 63;
    const int b    = lane & 15;
    const int kc   = lane >> 4;
    const int dcol = grp * 64 + dslc * 16 + w;
    const int bgl  = sgrp * 16 + b;
    const int row0 = sgrp * 16;
    const int fcol = grp * 16 + dslc * 4 + (w & 3);
    const int gid  = blkid * NTHR + tid;

    pack_wsum(ws + OFF_F_WSUM, eW1, eU1, gid);
    pack_wdeca_p(ws + OFF_F_WDECA, dU0, dW0, dw, gid);
    if (gid < ND) {
        float acc = db0[gid];
        for (int j = 0; j < Fsz; ++j) acc += db_[j] * dW0[(size_t)j * ND + gid];
        (ws + OFF_F_BF)[gid] = acc;
    }
    if (gid < Dsz * Fsz) {
        const int f = gid >> 9, k = gid & 511;
        (ws + OFF_F_DWT)[(size_t)f * Dsz + k] = dw[(size_t)k * Fsz + f];
    }
    const float* pWSUM = ws + OFF_F_WSUM;
    const float* pWDECA = ws + OFF_F_WDECA;
    const float* pBF = ws + OFF_F_BF;
    const float* pDWT = ws + OFF_F_DWT;
    gbar_all(fslots, blkid, 1);

    unsigned ep = 0;
    int cur = 0;
    float c_car = 0.f;

    for (int t = 0; t < Tsz; ++t) {
        stage_vec(XL, 644, 0, enc_in + (size_t)t * Fsz, row0, Tsz * Fsz, 128, 5);
        __syncthreads();
        float4 z = make_float4(0.f, 0.f, 0.f, 0.f);
        acc_segS(z, XL + b * 644 + kc * 32, eW0, kc * 32, 32, dcol);
        wait_grp(gslots, ep);
        stage_coh_T(XL, 644, 128, HT[cur], row0);
        __syncthreads();
        acc_segS(z, XL + b * 644 + 128 + kc * 128, eU0, kc * 128, 128, dcol);
        reduce4(z);
        float c1 = 0.f;
        if (lane < 16) {
            float h2 = lstm_fin(z, eb0, dcol, c_car, c1);
            st_coh(&HMT[(size_t)dcol * Bsz + bgl], h2);
        }
        arrive(&gslots[gm], ++ep);
        wait_grp(gslots, ep);
        stage_coh_T(XL, 516, 0, HMT, row0);
        __syncthreads();
        z = make_float4(0.f, 0.f, 0.f, 0.f);
        {
            const float4* wp = (const float4*)pWSUM + (size_t)dcol * 512 + kc * 128;
            const float* xp = XL + b * 516 + kc * 128;
            #pragma unroll 4
            for (int j = 0; j < 128; j += 4) {
                float4 x4 = *(const float4*)(xp + j);
                float4 w0 = wp[j], w1 = wp[j + 1], w2 = wp[j + 2], w3 = wp[j + 3];
                z.x += x4.x*w0.x + x4.y*w1.x + x4.z*w2.x + x4.w*w3.x;
                z.y += x4.x*w0.y + x4.y*w1.y + x4.z*w2.y + x4.w*w3.y;
                z.z += x4.x*w0.z + x4.y*w1.z + x4.z*w2.z + x4.w*w3.z;
                z.w += x4.x*w0.w + x4.y*w1.w + x4.z*w2.w + x4.w*w3.w;
            }
        }
        reduce4(z);
        if (lane < 16) {
            float c2;
            float h2 = lstm_fin(z, eb1, dcol, c1, c2);
            c_car = c2;
            st_coh(&HT[cur ^ 1][(size_t)dcol * Bsz + bgl], h2);
        }
        arrive(&gslots[gm], ++ep);
        cur ^= 1;
    }

    stage_vec(XL, 644, 0, dec_in, row0, Tsz * Fsz, 128, 5);
    __syncthreads();
    {
        float4 z = make_float4(0.f, 0.f, 0.f, 0.f);
        acc_segS(z, XL + b * 644 + kc * 32, dW0, kc * 32, 32, dcol);
        wait_grp(gslots, ep);
        stage_coh_T(XL, 644, 128, HT[cur], row0);
        __syncthreads();
        acc_segS(z, XL + b * 644 + 128 + kc * 128, dU0, kc * 128, 128, dcol);
        reduce4(z);
        if (lane < 16) {
            float cd;
            float h2 = lstm_fin(z, db0, dcol, c_car, cd);
            st_coh(&HMT[(size_t)dcol * Bsz + bgl], h2);
        }
        arrive(&gslots[gm], ++ep);
    }
    wait_grp(gslots, ep);
    stage_coh_T(XL, 1028, 0, HT[cur], row0);
    stage_coh_T(XL, 1028, 512, HMT, row0);
    __syncthreads();
    {
        float4 z = make_float4(0.f, 0.f, 0.f, 0.f);
        acc_segS(z, XL + b * 1028 + kc * 128, dU1, kc * 128, 128, dcol);
        acc_segS(z, XL + b * 1028 + 512 + kc * 128, dW1, kc * 128, 128, dcol);
        reduce4(z);
        if (lane < 16) {
            float c2;
            float h2 = lstm_fin(z, db1, dcol, c_car, c2);
            c_car = c2;
            st_coh(&HT[cur ^ 1][(size_t)dcol * Bsz + bgl], h2);
        }
    }
    arrive(&gslots[gm], ++ep);
    cur ^= 1;

    for (int t = 1; t < Tsz; ++t) {
        const int tt = Tsz - t;
        wait_grp(gslots, ep);
        stage_coh_T(XL, 1028, 0, HT[cur], row0);
        __syncthreads();
        {
            float4 z = make_float4(0.f, 0.f, 0.f, 0.f);
            const float4* wp = (const float4*)pWDECA + (size_t)dcol * 512 + kc * 128;
            const float* xp = XL + b * 1028 + kc * 128;
            #pragma unroll 4
            for (int j = 0; j < 128; j += 4) {
                float4 x4 = *(const float4*)(xp + j);
                float4 w0 = wp[j], w1 = wp[j + 1], w2 = wp[j + 2], w3 = wp[j + 3];
                z.x += x4.x*w0.x + x4.y*w1.x + x4.z*w2.x + x4.w*w3.x;
                z.y += x4.x*w0.y + x4.y*w1.y + x4.z*w2.y + x4.w*w3.y;
                z.z += x4.x*w0.z + x4.y*w1.z + x4.z*w2.z + x4.w*w3.z;
                z.w += x4.x*w0.w + x4.y*w1.w + x4.z*w2.w + x4.w*w3.w;
            }
            reduce4(z);
            out_part(XL, 1028, ORED, b, kc, w, fcol, pDWT);
            if (lane < 16) {
                float cd;
                float h2 = lstm_fin(z, pBF, dcol, c_car, cd);
                st_coh(&HMT[(size_t)dcol * Bsz + bgl], h2);
            }
        }
        arrive(&gslots[gm], ++ep);
        if (tid < 64) {
            const int bb = tid >> 2, ff = tid & 3;
            const int fc = grp * 16 + dslc * 4 + ff;
            const float* r = ORED + bb * 16 + ff * 4;
            float s = r[0] + r[1] + r[2] + r[3] + db_[fc];
            out[((size_t)(row0 + bb) * Tsz + tt) * Fsz + fc] = s;
        }
        wait_grp(gslots, ep);
        stage_coh_T(XL, 1028, 512, HMT, row0);
        __syncthreads();
        {
            float4 z = make_float4(0.f, 0.f, 0.f, 0.f);
            acc_segS(z, XL + b * 1028 + kc * 128, dU1, kc * 128, 128, dcol);
            acc_segS(z, XL + b * 1028 + 512 + kc * 128, dW1, kc * 128, 128, dcol);
            reduce4(z);
            if (lane < 16) {
                float c2;
                float h2 = lstm_fin(z, db1, dcol, c_car, c2);
                c_car = c2;
                st_coh(&HT[cur ^ 1][(size_t)dcol * Bsz + bgl], h2);
            }
        }
        arrive(&gslots[gm], ++ep);
        cur ^= 1;
    }

    wait_grp(gslots, ep);
    stage_coh_T(XL, 516, 0, HT[cur], row0);
    __syncthreads();
    out_part(XL, 516, ORED, b, kc, w, fcol, pDWT);
    __syncthreads();
    if (tid < 64) {
        const int bb = tid >> 2, ff = tid & 3;
        const int fc = grp * 16 + dslc * 4 + ff;
        const float* r = ORED + bb * 16 + ff * 4;
        float s = r[0] + r[1] + r[2] + r[3] + db_[fc];
        out[((size_t)(row0 + bb) * Tsz + 0) * Fsz + fc] = s;
    }
}

extern "C" void kernel_launch(void* const* d_in, const int* in_sizes, int n_in,
                              void* d_out, int out_size, void* d_ws, size_t ws_size,
                              hipStream_t stream) {
    (void)in_sizes; (void)n_in; (void)out_size;
    const float* enc_in = (const float*)d_in[0];
    const float* dec_in = (const float*)d_in[1];
    const float* eW0 = (const float*)d_in[2];
    const float* eU0 = (const float*)d_in[3];
    const float* eb0 = (const float*)d_in[4];
    const float* eW1 = (const float*)d_in[5];
    const float* eU1 = (const float*)d_in[6];
    const float* eb1 = (const float*)d_in[7];
    const float* dW0 = (const float*)d_in[8];
    const float* dU0 = (const float*)d_in[9];
    const float* db0 = (const float*)d_in[10];
    const float* dW1 = (const float*)d_in[11];
    const float* dU1 = (const float*)d_in[12];
    const float* db1 = (const float*)d_in[13];
    const float* dw  = (const float*)d_in[14];
    const float* db_ = (const float*)d_in[15];
    float* out = (float*)d_out;
    float* ws = (float*)d_ws;

    // zero: full-grid slots + 16x32 chain slots + HT0 (initial h = 0)
    hipMemsetAsync(d_ws, 0, (size_t)(OFF_HT0 + Dsz * Bsz) * sizeof(float), stream);

    if (ws_size >= (size_t)WS_PACKED_FLOATS * sizeof(float))
        lstm_ae_v9<<<NBLK, NTHR, 0, stream>>>(
            enc_in, dec_in, eW0, eU0, eb0, eW1, eU1, eb1,
            dW0, dU0, db0, dW1, dU1, db1, dw, db_, out, ws);
    else
        lstm_ae_fb<<<NBLK, NTHR, 0, stream>>>(
            enc_in, dec_in, eW0, eU0, eb0, eW1, eU1, eb1,
            dW0, dU0, db0, dW1, dU1, db1, dw, db_, out, ws);
}

// Round 4
// 7249.294 us; speedup vs baseline: 8.8890x; 1.4167x over previous
//
#include <hip/hip_runtime.h>

// =====================================================================
// LSTM autoencoder v10: v9 dual-chain structure + cheap reductions.
// The v9 reduce (red32 x4 = 80 ds_bpermute/thread/phase) was the
// largest LDS-pipe consumer. Replaced by:
//  - halved-payload exchange for bit5 (kh, 8 shfl) and bit3 (4 shfl):
//    only the floats the partner needs are moved;
//  - DPP (VALU-pipe) steps for bits 0,1,2: quad_perm xor1/xor2 and
//    row_half_mirror (exact once bits 0,1 are uniform). 0 LDS ops.
// 80 -> 12 LDS shuffle ops per reduce; out_part 20 -> 3.
// Result ownership: lanes (kc&7)==0, sample = qb2*4 + kh*2 + b3
// (fixed per lane -> c-carry register stays valid across phases).
// Everything else (barriers, packing, LDS layout) identical to v9.
// =====================================================================

#define Bsz 128
#define Tsz 128
#define Fsz 128
#define Dsz 512
#define ND  2048
#define NBLK 256
#define NTHR 1024

// ---- ws layout (float offsets) ----
#define OFF_HT0  1024
#define OFF_HT1  (OFF_HT0 + Dsz*Bsz)
#define OFF_HMT  (OFF_HT1 + Dsz*Bsz)
#define OFF_WEND (OFF_HMT + Dsz*Bsz)
// packed weights (gate-interleaved float4: Wp4[dcol*K + k] = {i,f,g,o})
#define OFF_P_EW0   OFF_WEND
#define OFF_P_EU0   (OFF_P_EW0 + Fsz*ND)
#define OFF_P_WSUM  (OFF_P_EU0 + Dsz*ND)
#define OFF_P_WDECA (OFF_P_WSUM + Dsz*ND)
#define OFF_P_DW0   (OFF_P_WDECA + Dsz*ND)
#define OFF_P_DU0   (OFF_P_DW0 + Fsz*ND)
#define OFF_P_DW1   (OFF_P_DU0 + Dsz*ND)
#define OFF_P_DU1   (OFF_P_DW1 + Dsz*ND)
#define OFF_P_BF    (OFF_P_DU1 + Dsz*ND)
#define OFF_P_DWT   (OFF_P_BF + ND)
#define WS_PACKED_FLOATS (OFF_P_DWT + Dsz*Fsz)
// fallback layout
#define OFF_F_WSUM  OFF_WEND
#define OFF_F_WDECA (OFF_F_WSUM + Dsz*ND)
#define OFF_F_BF    (OFF_F_WDECA + Dsz*ND)
#define OFF_F_DWT   (OFF_F_BF + ND)
#define WS_FALLBACK_FLOATS (OFF_F_DWT + Dsz*Fsz)

#define NR 12   // LDS row stride: 8 data + 4 pad floats (16B aligned)

__device__ __forceinline__ float sigf(float x) {
    return 1.0f / (1.0f + __expf(-x));
}
__device__ __forceinline__ float ld_coh(const float* p) {
    return __hip_atomic_load((float*)p, __ATOMIC_RELAXED, __HIP_MEMORY_SCOPE_AGENT);
}
__device__ __forceinline__ void st_coh(float* p, float v) {
    __hip_atomic_store(p, v, __ATOMIC_RELAXED, __HIP_MEMORY_SCOPE_AGENT);
}

// ---- split group barrier (32 members, per-chain slot arrays) ----
__device__ __forceinline__ void arrive(unsigned* slot, unsigned ep) {
    __syncthreads();
    if (threadIdx.x == 0)
        __hip_atomic_store(slot, ep, __ATOMIC_RELEASE, __HIP_MEMORY_SCOPE_AGENT);
}
__device__ __forceinline__ void wait_grp(unsigned* gslots, unsigned ep) {
    if (threadIdx.x < 64) {
        for (;;) {
            unsigned v = (threadIdx.x < 32)
                ? __hip_atomic_load(&gslots[threadIdx.x], __ATOMIC_RELAXED,
                                    __HIP_MEMORY_SCOPE_AGENT)
                : ep;
            if (__all(v >= ep)) break;
            __builtin_amdgcn_s_sleep(1);
        }
    }
    __syncthreads();
}
__device__ __forceinline__ void gbar_all(unsigned* slots, int blkid, unsigned ep) {
    __syncthreads();
    if (threadIdx.x == 0) {
        __threadfence();
        __hip_atomic_store(&slots[blkid], ep, __ATOMIC_RELEASE,
                           __HIP_MEMORY_SCOPE_AGENT);
    }
    if (threadIdx.x < 64) {
        for (;;) {
            unsigned mn = ~0u;
            #pragma unroll
            for (int q = 0; q < 4; ++q) {
                unsigned v = __hip_atomic_load(&slots[threadIdx.x * 4 + q],
                                               __ATOMIC_RELAXED, __HIP_MEMORY_SCOPE_AGENT);
                mn = min(mn, v);
            }
            if (__all(mn >= ep)) break;
            __builtin_amdgcn_s_sleep(1);
        }
        if (threadIdx.x == 0) __threadfence();
    }
    __syncthreads();
}

// ---- P0 packing (identical to v6/v8/v9) ----
__device__ void pack_gate(float* dst, const float* src, int K, int kshift, int gid) {
    const int total = K * Dsz;
    for (int u = gid; u < total; u += NBLK * NTHR) {
        const int dd = u >> kshift;
        const int k = u & (K - 1);
        const float* sp = src + (size_t)k * ND + dd;
        ((float4*)dst)[u] = make_float4(sp[0], sp[Dsz], sp[2 * Dsz], sp[3 * Dsz]);
    }
}
__device__ void pack_wsum(float* dst, const float* a, const float* bsrc, int gid) {
    for (int u = gid; u < Dsz * Dsz; u += NBLK * NTHR) {
        const int dd = u >> 9, k = u & 511;
        const float* pa = a + (size_t)k * ND + dd;
        const float* pb = bsrc + (size_t)k * ND + dd;
        ((float4*)dst)[u] = make_float4(pa[0] + pb[0], pa[Dsz] + pb[Dsz],
                                        pa[2*Dsz] + pb[2*Dsz], pa[3*Dsz] + pb[3*Dsz]);
    }
}
__device__ void pack_wdeca_p(float* dst, const float* dU0, const float* dW0,
                             const float* dw, int gid) {
    for (int u = gid; u < Dsz * Dsz; u += NBLK * NTHR) {
        const int dd = u >> 9, k = u & 511;
        const float* pu = dU0 + (size_t)k * ND + dd;
        float a0 = pu[0], a1 = pu[Dsz], a2 = pu[2*Dsz], a3 = pu[3*Dsz];
        const float* dwr = dw + k * Fsz;
        for (int j = 0; j < Fsz; ++j) {
            const float wv = dwr[j];
            const float* dr = dW0 + (size_t)j * ND + dd;
            a0 += wv * dr[0]; a1 += wv * dr[Dsz];
            a2 += wv * dr[2*Dsz]; a3 += wv * dr[3*Dsz];
        }
        ((float4*)dst)[u] = make_float4(a0, a1, a2, a3);
    }
}

// =====================================================================
// ======================  v10 kernel  =================================
// =====================================================================

// stage 512 h rows (8 samples) from transposed coherent buffer
__device__ __forceinline__ void stageH9(float* XL, const float* HTsrc, int sr, int rbase) {
    #pragma unroll
    for (int ii = 0; ii < 4; ++ii) {
        const int i = (int)threadIdx.x + ii * NTHR;
        const int r = i >> 3, bb = i & 7;
        XL[(rbase + r) * NR + bb] = ld_coh(HTsrc + (size_t)r * Bsz + sr + bb);
    }
}
// stage 128 x rows (8 samples), 1 elem/thread
__device__ __forceinline__ void stageX9(float* XL, const float* src, int sr, int rbase) {
    const int r = (int)threadIdx.x & 127, bb = (int)threadIdx.x >> 7;
    XL[(rbase + r) * NR + bb] = src[(size_t)(sr + bb) * (Tsz * Fsz) + r];
}

#define FMA16(A0,A1,A2,A3,x4,w4) \
    A0.x += x4.x*w4.x; A0.y += x4.x*w4.y; A0.z += x4.x*w4.z; A0.w += x4.x*w4.w; \
    A1.x += x4.y*w4.x; A1.y += x4.y*w4.y; A1.z += x4.y*w4.z; A1.w += x4.y*w4.w; \
    A2.x += x4.z*w4.x; A2.y += x4.z*w4.y; A2.z += x4.z*w4.z; A2.w += x4.z*w4.w; \
    A3.x += x4.w*w4.x; A3.y += x4.w*w4.y; A3.z += x4.w*w4.z; A3.w += x4.w*w4.w;

// consume NJ*32 K-rows: Wp pre-offset by koff; Xb pre-offset by
// (rowbase+koff)*NR + qb2*4. Row step per j = 32.
template<int NJ>
__device__ __forceinline__ void consTv(const float4* __restrict__ Wp,
        const float* __restrict__ Xb,
        float4& A0, float4& A1, float4& A2, float4& A3)
{
    #pragma unroll 8
    for (int j = 0; j < NJ; ++j) {
        const float4 x4 = *(const float4*)(Xb + j * (32 * NR));
        const float4 w4 = Wp[j * 32];
        FMA16(A0, A1, A2, A3, x4, w4)
    }
}

// ---- cheap cross-lane reduction ----
// DPP helpers: v + v(partner), VALU pipe (no LDS traffic).
__device__ __forceinline__ float dppx1(float v) {   // xor 1 (quad_perm [1,0,3,2])
    return v + __int_as_float(__builtin_amdgcn_mov_dpp(
        __float_as_int(v), 0xB1, 0xf, 0xf, true));
}
__device__ __forceinline__ float dppx2(float v) {   // xor 2 (quad_perm [2,3,0,1])
    return v + __int_as_float(__builtin_amdgcn_mov_dpp(
        __float_as_int(v), 0x4E, 0xf, 0xf, true));
}
__device__ __forceinline__ float dpphm(float v) {   // i^7 within 8 (row_half_mirror)
    return v + __int_as_float(__builtin_amdgcn_mov_dpp(
        __float_as_int(v), 0x141, 0xf, 0xf, true));
}
// halved exchange: cond==false keeps lo (sends hi), cond==true keeps hi (sends lo)
#define HXCH(lo, hi, mask, cond) { \
    float s_ = (cond) ? (lo) : (hi); \
    float r_ = __shfl_xor(s_, mask); \
    if (cond) (hi) += r_; else (lo) += r_; }

// reduce A0..A3 (samples qb2*4+0..3) over kc bits{0,1,2,3} and kh(bit5).
// Returns Z = gate-sums for sample qb2*4 + kh*2 + b3 (uniform over kc bits 0..2).
__device__ __forceinline__ float4 redZ(float4 A0, float4 A1, float4 A2, float4 A3,
                                       bool khb, bool b3b)
{
    HXCH(A0.x, A2.x, 32, khb) HXCH(A0.y, A2.y, 32, khb)
    HXCH(A0.z, A2.z, 32, khb) HXCH(A0.w, A2.w, 32, khb)
    HXCH(A1.x, A3.x, 32, khb) HXCH(A1.y, A3.y, 32, khb)
    HXCH(A1.z, A3.z, 32, khb) HXCH(A1.w, A3.w, 32, khb)
    float4 B0, B1;
    B0.x = khb ? A2.x : A0.x; B0.y = khb ? A2.y : A0.y;
    B0.z = khb ? A2.z : A0.z; B0.w = khb ? A2.w : A0.w;
    B1.x = khb ? A3.x : A1.x; B1.y = khb ? A3.y : A1.y;
    B1.z = khb ? A3.z : A1.z; B1.w = khb ? A3.w : A1.w;
    HXCH(B0.x, B1.x, 8, b3b) HXCH(B0.y, B1.y, 8, b3b)
    HXCH(B0.z, B1.z, 8, b3b) HXCH(B0.w, B1.w, 8, b3b)
    float4 Z;
    Z.x = b3b ? B1.x : B0.x; Z.y = b3b ? B1.y : B0.y;
    Z.z = b3b ? B1.z : B0.z; Z.w = b3b ? B1.w : B0.w;
    Z.x = dppx1(Z.x); Z.y = dppx1(Z.y); Z.z = dppx1(Z.z); Z.w = dppx1(Z.w);
    Z.x = dppx2(Z.x); Z.y = dppx2(Z.y); Z.z = dppx2(Z.z); Z.w = dppx2(Z.w);
    Z.x = dpphm(Z.x); Z.y = dpphm(Z.y); Z.z = dpphm(Z.z); Z.w = dpphm(Z.w);
    return Z;
}

__device__ __forceinline__ float fin4b(float4 z, const float* bias, int dcol,
                                       float cprev, float& c2o) {
    float gi = sigf(z.x + bias[dcol]);
    float gf = sigf(z.y + bias[Dsz + dcol]);
    float gg = fmaxf(z.z + bias[2 * Dsz + dcol], 0.f);
    float go = sigf(z.w + bias[3 * Dsz + dcol]);
    float c2 = gf * cprev + gi * gg;
    c2o = c2;
    return go * fmaxf(c2, 0.f);
}

// fused dense-row partials for one chain: ORED[sample][ff*4+qk]
__device__ __forceinline__ void out_part9(const float* XL, const float* DWL, float* ORED,
                                          int xo, int koff, int wv,
                                          bool khb, bool b3b, bool own, int sown)
{
    const int ff = wv & 3, qk = wv >> 2;
    float o0 = 0.f, o1 = 0.f, o2 = 0.f, o3 = 0.f;
    const float* Xb = XL + qk * 128 * NR + xo;
    const float* Wb = DWL + ff * 512 + qk * 128 + koff;
    #pragma unroll
    for (int j = 0; j < 4; ++j) {
        const float4 x4 = *(const float4*)(Xb + j * (32 * NR));
        const float w = Wb[j * 32];
        o0 += x4.x * w; o1 += x4.y * w; o2 += x4.z * w; o3 += x4.w * w;
    }
    HXCH(o0, o2, 32, khb) HXCH(o1, o3, 32, khb)
    float p0 = khb ? o2 : o0;
    float p1 = khb ? o3 : o1;
    HXCH(p0, p1, 8, b3b)
    float o = b3b ? p1 : p0;
    o = dppx1(o); o = dppx2(o); o = dpphm(o);
    if (own) ORED[sown * 16 + ff * 4 + qk] = o;
}

__global__ void __launch_bounds__(NTHR, 1)
lstm_ae_v10(const float* enc_in, const float* dec_in,
            const float* eW0, const float* eU0, const float* eb0,
            const float* eW1, const float* eU1, const float* eb1,
            const float* dW0, const float* dU0, const float* db0,
            const float* dW1, const float* dU1, const float* db1,
            const float* dw, const float* db_, float* out, float* ws)
{
    __shared__ float XLA[1024 * NR];   // 48 KB chain A: h rows 0..511, x/hA rows 512+
    __shared__ float XLB[1024 * NR];   // 48 KB chain B
    __shared__ float DWL[4 * 512];     //  8 KB resident dwT slice (4 fcols)
    __shared__ float OREDA[128];
    __shared__ float OREDB[128];

    unsigned* fslots = (unsigned*)ws;
    float* HT[2] = { ws + OFF_HT0, ws + OFF_HT1 };
    float* HMT = ws + OFF_HMT;

    const int blkid = blockIdx.x;
    const int grp  = blkid & 7;       // XCD / dcol-slice owner
    const int mem  = blkid >> 3;
    const int sgrp = mem & 7;
    const int dslc = mem >> 3;
    const int gm   = dslc * 8 + grp;  // member id (0..31)
    const int chA  = sgrp * 2, chB = chA + 1;     // 16 chains, 32 slots each
    unsigned* gsA = (unsigned*)ws + 256 + chA * 32;
    unsigned* gsB = (unsigned*)ws + 256 + chB * 32;
    const int srA = sgrp * 16;        // chain A samples [srA, srA+8)
    const int srB = sgrp * 16 + 8;

    const int tid  = threadIdx.x;
    const int wv   = tid >> 6;
    const int lane = tid & 63;
    const int kh   = lane >> 5;          // K-half bit
    const int qb2  = (lane >> 4) & 1;    // sample quad (of 2)
    const int kc   = lane & 15;          // K interleave slot
    const int koff = kh * 16 + kc;       // K offset within 32-row step
    const int dcol = grp * 64 + dslc * 16 + wv;
    const int fcol0 = grp * 16 + dslc * 4;
    const int gid  = blkid * NTHR + tid;
    const bool khb = (kh != 0);
    const bool b3b = ((kc & 8) != 0);
    const bool own = ((kc & 7) == 0);    // one lane per owned sample
    const int sown = qb2 * 4 + kh * 2 + ((kc >> 3) & 1);
    const int xo   = koff * NR + qb2 * 4; // per-thread LDS read base

    // ---- P0 (identical to v9) ----
    pack_gate(ws + OFF_P_EW0, eW0, Fsz, 7, gid);
    pack_gate(ws + OFF_P_EU0, eU0, Dsz, 9, gid);
    pack_wsum(ws + OFF_P_WSUM, eW1, eU1, gid);
    pack_wdeca_p(ws + OFF_P_WDECA, dU0, dW0, dw, gid);
    pack_gate(ws + OFF_P_DW0, dW0, Fsz, 7, gid);
    pack_gate(ws + OFF_P_DU0, dU0, Dsz, 9, gid);
    pack_gate(ws + OFF_P_DW1, dW1, Dsz, 9, gid);
    pack_gate(ws + OFF_P_DU1, dU1, Dsz, 9, gid);
    if (gid < ND) {
        float acc = db0[gid];
        for (int j = 0; j < Fsz; ++j) acc += db_[j] * dW0[(size_t)j * ND + gid];
        (ws + OFF_P_BF)[gid] = acc;
    }
    if (gid < Dsz * Fsz) {
        const int f = gid >> 9, k = gid & 511;
        (ws + OFF_P_DWT)[(size_t)f * Dsz + k] = dw[(size_t)k * Fsz + f];
    }
    gbar_all(fslots, blkid, 1);

    // resident dwT slice for this block's 4 fcols
    #pragma unroll
    for (int ii = 0; ii < 2; ++ii) {
        const int i = tid + ii * NTHR;
        DWL[i] = (ws + OFF_P_DWT)[(size_t)(fcol0 + (i >> 9)) * Dsz + (i & 511)];
    }
    __syncthreads();

    const float* pBF = ws + OFF_P_BF;
    const float4* W_EW0   = (const float4*)(ws + OFF_P_EW0)   + (size_t)dcol * 128 + koff;
    const float4* W_EU0   = (const float4*)(ws + OFF_P_EU0)   + (size_t)dcol * 512 + koff;
    const float4* W_WSUM  = (const float4*)(ws + OFF_P_WSUM)  + (size_t)dcol * 512 + koff;
    const float4* W_WDECA = (const float4*)(ws + OFF_P_WDECA) + (size_t)dcol * 512 + koff;
    const float4* W_DW0   = (const float4*)(ws + OFF_P_DW0)   + (size_t)dcol * 128 + koff;
    const float4* W_DU0   = (const float4*)(ws + OFF_P_DU0)   + (size_t)dcol * 512 + koff;
    const float4* W_DW1   = (const float4*)(ws + OFF_P_DW1)   + (size_t)dcol * 512 + koff;
    const float4* W_DU1   = (const float4*)(ws + OFF_P_DU1)   + (size_t)dcol * 512 + koff;

    unsigned epA = 0, epB = 0;
    int cur = 0;
    float cA = 0.f, cmA = 0.f, cB = 0.f, cmB = 0.f;
    const float4 Z4 = make_float4(0.f, 0.f, 0.f, 0.f);

    // ======================= encoder =======================
    for (int t = 0; t < Tsz; ++t) {
        stageX9(XLA, enc_in + (size_t)t * Fsz, srA, 512);
        stageX9(XLB, enc_in + (size_t)t * Fsz, srB, 512);
        __syncthreads();
        // ---- A L0 ----
        {
            float4 A0 = Z4, A1 = Z4, A2 = Z4, A3 = Z4;
            consTv<4>(W_EW0, XLA + 512 * NR + xo, A0, A1, A2, A3);
            wait_grp(gsA, epA);
            stageH9(XLA, HT[cur], srA, 0);
            __syncthreads();
            consTv<16>(W_EU0, XLA + xo, A0, A1, A2, A3);
            float4 Z = redZ(A0, A1, A2, A3, khb, b3b);
            if (own) {
                float cn; float h2 = fin4b(Z, eb0, dcol, cA, cn); cmA = cn;
                st_coh(&HMT[(size_t)dcol * Bsz + srA + sown], h2);
            }
            arrive(&gsA[gm], ++epA);
        }
        // ---- B L0 ----
        {
            float4 A0 = Z4, A1 = Z4, A2 = Z4, A3 = Z4;
            consTv<4>(W_EW0, XLB + 512 * NR + xo, A0, A1, A2, A3);
            wait_grp(gsB, epB);
            stageH9(XLB, HT[cur], srB, 0);
            __syncthreads();
            consTv<16>(W_EU0, XLB + xo, A0, A1, A2, A3);
            float4 Z = redZ(A0, A1, A2, A3, khb, b3b);
            if (own) {
                float cn; float h2 = fin4b(Z, eb0, dcol, cB, cn); cmB = cn;
                st_coh(&HMT[(size_t)dcol * Bsz + srB + sown], h2);
            }
            arrive(&gsB[gm], ++epB);
        }
        // ---- A L1 ----
        {
            wait_grp(gsA, epA);
            stageH9(XLA, HMT, srA, 0);
            __syncthreads();
            float4 A0 = Z4, A1 = Z4, A2 = Z4, A3 = Z4;
            consTv<16>(W_WSUM, XLA + xo, A0, A1, A2, A3);
            float4 Z = redZ(A0, A1, A2, A3, khb, b3b);
            if (own) {
                float cn; float h2 = fin4b(Z, eb1, dcol, cmA, cn); cA = cn;
                st_coh(&HT[cur ^ 1][(size_t)dcol * Bsz + srA + sown], h2);
            }
            arrive(&gsA[gm], ++epA);
        }
        // ---- B L1 ----
        {
            wait_grp(gsB, epB);
            stageH9(XLB, HMT, srB, 0);
            __syncthreads();
            float4 A0 = Z4, A1 = Z4, A2 = Z4, A3 = Z4;
            consTv<16>(W_WSUM, XLB + xo, A0, A1, A2, A3);
            float4 Z = redZ(A0, A1, A2, A3, khb, b3b);
            if (own) {
                float cn; float h2 = fin4b(Z, eb1, dcol, cmB, cn); cB = cn;
                st_coh(&HT[cur ^ 1][(size_t)dcol * Bsz + srB + sown], h2);
            }
            arrive(&gsB[gm], ++epB);
        }
        cur ^= 1;
    }

    // ======================= decoder t=0 =======================
    {
        stageX9(XLA, dec_in, srA, 512);
        stageX9(XLB, dec_in, srB, 512);
        __syncthreads();
        // A L0 (c discarded)
        {
            float4 A0 = Z4, A1 = Z4, A2 = Z4, A3 = Z4;
            consTv<4>(W_DW0, XLA + 512 * NR + xo, A0, A1, A2, A3);
            wait_grp(gsA, epA);
            stageH9(XLA, HT[cur], srA, 0);
            __syncthreads();
            consTv<16>(W_DU0, XLA + xo, A0, A1, A2, A3);
            float4 Z = redZ(A0, A1, A2, A3, khb, b3b);
            if (own) {
                float cd; float h2 = fin4b(Z, db0, dcol, cA, cd);
                st_coh(&HMT[(size_t)dcol * Bsz + srA + sown], h2);
            }
            arrive(&gsA[gm], ++epA);
        }
        // B L0
        {
            float4 A0 = Z4, A1 = Z4, A2 = Z4, A3 = Z4;
            consTv<4>(W_DW0, XLB + 512 * NR + xo, A0, A1, A2, A3);
            wait_grp(gsB, epB);
            stageH9(XLB, HT[cur], srB, 0);
            __syncthreads();
            consTv<16>(W_DU0, XLB + xo, A0, A1, A2, A3);
            float4 Z = redZ(A0, A1, A2, A3, khb, b3b);
            if (own) {
                float cd; float h2 = fin4b(Z, db0, dcol, cB, cd);
                st_coh(&HMT[(size_t)dcol * Bsz + srB + sown], h2);
            }
            arrive(&gsB[gm], ++epB);
        }
        // A L1: h_old (rows 0..511) @ dU1 + hA (rows 512+) @ dW1; old carry
        {
            wait_grp(gsA, epA);
            stageH9(XLA, HMT, srA, 512);
            __syncthreads();
            float4 A0 = Z4, A1 = Z4, A2 = Z4, A3 = Z4;
            consTv<16>(W_DU1, XLA + xo, A0, A1, A2, A3);
            consTv<16>(W_DW1, XLA + 512 * NR + xo, A0, A1, A2, A3);
            float4 Z = redZ(A0, A1, A2, A3, khb, b3b);
            if (own) {
                float cn; float h2 = fin4b(Z, db1, dcol, cA, cn); cA = cn;
                st_coh(&HT[cur ^ 1][(size_t)dcol * Bsz + srA + sown], h2);
            }
            arrive(&gsA[gm], ++epA);
        }
        // B L1
        {
            wait_grp(gsB, epB);
            stageH9(XLB, HMT, srB, 512);
            __syncthreads();
            float4 A0 = Z4, A1 = Z4, A2 = Z4, A3 = Z4;
            consTv<16>(W_DU1, XLB + xo, A0, A1, A2, A3);
            consTv<16>(W_DW1, XLB + 512 * NR + xo, A0, A1, A2, A3);
            float4 Z = redZ(A0, A1, A2, A3, khb, b3b);
            if (own) {
                float cn; float h2 = fin4b(Z, db1, dcol, cB, cn); cB = cn;
                st_coh(&HT[cur ^ 1][(size_t)dcol * Bsz + srB + sown], h2);
            }
            arrive(&gsB[gm], ++epB);
        }
        cur ^= 1;
    }

    // ======================= decoder t=1..127 =======================
    for (int t = 1; t < Tsz; ++t) {
        const int tt = Tsz - t;
        // ---- A L0 folded + fused out partials ----
        {
            wait_grp(gsA, epA);
            stageH9(XLA, HT[cur], srA, 0);
            __syncthreads();
            float4 A0 = Z4, A1 = Z4, A2 = Z4, A3 = Z4;
            consTv<16>(W_WDECA, XLA + xo, A0, A1, A2, A3);
            out_part9(XLA, DWL, OREDA, xo, koff, wv, khb, b3b, own, sown);
            float4 Z = redZ(A0, A1, A2, A3, khb, b3b);
            if (own) {
                float cd; float h2 = fin4b(Z, pBF, dcol, cA, cd);
                st_coh(&HMT[(size_t)dcol * Bsz + srA + sown], h2);
            }
            arrive(&gsA[gm], ++epA);
            if (tid < 32) {
                const int bb = tid >> 2, ff = tid & 3;
                const int fc = fcol0 + ff;
                const float* r = OREDA + bb * 16 + ff * 4;
                float s = r[0] + r[1] + r[2] + r[3] + db_[fc];
                out[((size_t)(srA + bb) * Tsz + tt) * Fsz + fc] = s;
            }
        }
        // ---- B L0 ----
        {
            wait_grp(gsB, epB);
            stageH9(XLB, HT[cur], srB, 0);
            __syncthreads();
            float4 A0 = Z4, A1 = Z4, A2 = Z4, A3 = Z4;
            consTv<16>(W_WDECA, XLB + xo, A0, A1, A2, A3);
            out_part9(XLB, DWL, OREDB, xo, koff, wv, khb, b3b, own, sown);
            float4 Z = redZ(A0, A1, A2, A3, khb, b3b);
            if (own) {
                float cd; float h2 = fin4b(Z, pBF, dcol, cB, cd);
                st_coh(&HMT[(size_t)dcol * Bsz + srB + sown], h2);
            }
            arrive(&gsB[gm], ++epB);
            if (tid < 32) {
                const int bb = tid >> 2, ff = tid & 3;
                const int fc = fcol0 + ff;
                const float* r = OREDB + bb * 16 + ff * 4;
                float s = r[0] + r[1] + r[2] + r[3] + db_[fc];
                out[((size_t)(srB + bb) * Tsz + tt) * Fsz + fc] = s;
            }
        }
        // ---- A L1 ----
        {
            wait_grp(gsA, epA);
            stageH9(XLA, HMT, srA, 512);
            __syncthreads();
            float4 A0 = Z4, A1 = Z4, A2 = Z4, A3 = Z4;
            consTv<16>(W_DU1, XLA + xo, A0, A1, A2, A3);
            consTv<16>(W_DW1, XLA + 512 * NR + xo, A0, A1, A2, A3);
            float4 Z = redZ(A0, A1, A2, A3, khb, b3b);
            if (own) {
                float cn; float h2 = fin4b(Z, db1, dcol, cA, cn); cA = cn;
                st_coh(&HT[cur ^ 1][(size_t)dcol * Bsz + srA + sown], h2);
            }
            arrive(&gsA[gm], ++epA);
        }
        // ---- B L1 ----
        {
            wait_grp(gsB, epB);
            stageH9(XLB, HMT, srB, 512);
            __syncthreads();
            float4 A0 = Z4, A1 = Z4, A2 = Z4, A3 = Z4;
            consTv<16>(W_DU1, XLB + xo, A0, A1, A2, A3);
            consTv<16>(W_DW1, XLB + 512 * NR + xo, A0, A1, A2, A3);
            float4 Z = redZ(A0, A1, A2, A3, khb, b3b);
            if (own) {
                float cn; float h2 = fin4b(Z, db1, dcol, cB, cn); cB = cn;
                st_coh(&HT[cur ^ 1][(size_t)dcol * Bsz + srB + sown], h2);
            }
            arrive(&gsB[gm], ++epB);
        }
        cur ^= 1;
    }

    // ======================= final out_127 -> row 0 =======================
    wait_grp(gsA, epA);
    stageH9(XLA, HT[cur], srA, 0);
    __syncthreads();
    out_part9(XLA, DWL, OREDA, xo, koff, wv, khb, b3b, own, sown);
    wait_grp(gsB, epB);
    stageH9(XLB, HT[cur], srB, 0);
    __syncthreads();
    out_part9(XLB, DWL, OREDB, xo, koff, wv, khb, b3b, own, sown);
    __syncthreads();
    if (tid < 64) {
        const int half = tid >> 5;            // 0 = chain A, 1 = chain B
        const int l = tid & 31;
        const int bb = l >> 2, ff = l & 3;
        const int fc = fcol0 + ff;
        const float* ored = half ? OREDB : OREDA;
        const int sr = half ? srB : srA;
        const float* r = ored + bb * 16 + ff * 4;
        float s = r[0] + r[1] + r[2] + r[3] + db_[fc];
        out[((size_t)(sr + bb) * Tsz + 0) * Fsz + fc] = s;
    }
}

// =====================================================================
// ======================  v8 fallback kernel  =========================
// =====================================================================

__device__ __forceinline__ void stage_vec(float* XL, int xstr, int dstoff,
        const float* src, int row0, int ld, int klen, int c4shift) {
    const int q = klen >> 2;
    const int n4 = q * 16;
    for (int i = threadIdx.x; i < n4; i += NTHR) {
        const int row = i >> c4shift;
        const int c4 = i & (q - 1);
        float4 v = *(const float4*)(src + (size_t)(row0 + row) * ld + (c4 << 2));
        *(float4*)(XL + row * xstr + dstoff + (c4 << 2)) = v;
    }
}
__device__ __forceinline__ void stage_coh_T(float* XL, int xstr, int dstoff,
        const float* HTsrc, int row0) {
    for (int i = threadIdx.x; i < Dsz * 16; i += NTHR) {
        const int d = i >> 4;
        const int bb = i & 15;
        XL[bb * xstr + dstoff + d] = ld_coh(HTsrc + (size_t)d * Bsz + row0 + bb);
    }
}
__device__ __forceinline__ void acc_segS(float4& z, const float* xp,
                                         const float* W, int kbase, int ksub, int dcol) {
    for (int j = 0; j < ksub; ++j) {
        const float x = xp[j];
        const float* wr = W + (size_t)(kbase + j) * ND + dcol;
        z.x += x * wr[0];
        z.y += x * wr[Dsz];
        z.z += x * wr[2 * Dsz];
        z.w += x * wr[3 * Dsz];
    }
}
__device__ __forceinline__ void reduce4(float4& z) {
    z.x += __shfl_xor(z.x, 16); z.x += __shfl_xor(z.x, 32);
    z.y += __shfl_xor(z.y, 16); z.y += __shfl_xor(z.y, 32);
    z.z += __shfl_xor(z.z, 16); z.z += __shfl_xor(z.z, 32);
    z.w += __shfl_xor(z.w, 16); z.w += __shfl_xor(z.w, 32);
}
__device__ __forceinline__ float lstm_fin(float4 z, const float* bias, int dcol,
                                          float cprev, float& c2out) {
    float gi = sigf(z.x + bias[dcol]);
    float gf = sigf(z.y + bias[Dsz + dcol]);
    float gg = fmaxf(z.z + bias[2 * Dsz + dcol], 0.f);
    float go = sigf(z.w + bias[3 * Dsz + dcol]);
    float c2 = gf * cprev + gi * gg;
    c2out = c2;
    return go * fmaxf(c2, 0.f);
}
__device__ __forceinline__ void out_part(const float* XL, int xstr, float* ORED,
                                         int b, int kc, int w, int fcol,
                                         const float* dwT) {
    const int q = w >> 2;
    const float* xp = XL + b * xstr + q * 128 + kc * 32;
    const float* wt = dwT + (size_t)fcol * Dsz + q * 128 + kc * 32;
    float acc = 0.f;
    #pragma unroll
    for (int j = 0; j < 32; j += 4) {
        float4 x4 = *(const float4*)(xp + j);
        float4 w4 = *(const float4*)(wt + j);
        acc += x4.x * w4.x + x4.y * w4.y + x4.z * w4.z + x4.w * w4.w;
    }
    acc += __shfl_xor(acc, 16); acc += __shfl_xor(acc, 32);
    if ((threadIdx.x & 63) < 16) ORED[b * 16 + (w & 3) * 4 + q] = acc;
}

__global__ void __launch_bounds__(NTHR, 1)
lstm_ae_fb(const float* enc_in, const float* dec_in,
           const float* eW0, const float* eU0, const float* eb0,
           const float* eW1, const float* eU1, const float* eb1,
           const float* dW0, const float* dU0, const float* db0,
           const float* dW1, const float* dU1, const float* db1,
           const float* dw, const float* db_, float* out, float* ws)
{
    __shared__ float XL[16 * 1028];
    __shared__ float ORED[256];

    unsigned* fslots = (unsigned*)ws;
    float* HT[2] = { ws + OFF_HT0, ws + OFF_HT1 };
    float* HMT = ws + OFF_HMT;

    const int blkid = blockIdx.x;
    const int grp  = blkid & 7;
    const int mem  = blkid >> 3;
    const int sgrp = mem & 7;
    const int dslc = mem >> 3;
    const int gm   = dslc * 8 + grp;
    unsigned* gslots = (unsigned*)ws + 256 + sgrp * 64;

    const int tid  = threadIdx.x;
    const int w    = tid >> 6;
    const int lane = tid & 63;
    const int b    = lane & 15;
    const int kc   = lane >> 4;
    const int dcol = grp * 64 + dslc * 16 + w;
    const int bgl  = sgrp * 16 + b;
    const int row0 = sgrp * 16;
    const int fcol = grp * 16 + dslc * 4 + (w & 3);
    const int gid  = blkid * NTHR + tid;

    pack_wsum(ws + OFF_F_WSUM, eW1, eU1, gid);
    pack_wdeca_p(ws + OFF_F_WDECA, dU0, dW0, dw, gid);
    if (gid < ND) {
        float acc = db0[gid];
        for (int j = 0; j < Fsz; ++j) acc += db_[j] * dW0[(size_t)j * ND + gid];
        (ws + OFF_F_BF)[gid] = acc;
    }
    if (gid < Dsz * Fsz) {
        const int f = gid >> 9, k = gid & 511;
        (ws + OFF_F_DWT)[(size_t)f * Dsz + k] = dw[(size_t)k * Fsz + f];
    }
    const float* pWSUM = ws + OFF_F_WSUM;
    const float* pWDECA = ws + OFF_F_WDECA;
    const float* pBF = ws + OFF_F_BF;
    const float* pDWT = ws + OFF_F_DWT;
    gbar_all(fslots, blkid, 1);

    unsigned ep = 0;
    int cur = 0;
    float c_car = 0.f;

    for (int t = 0; t < Tsz; ++t) {
        stage_vec(XL, 644, 0, enc_in + (size_t)t * Fsz, row0, Tsz * Fsz, 128, 5);
        __syncthreads();
        float4 z = make_float4(0.f, 0.f, 0.f, 0.f);
        acc_segS(z, XL + b * 644 + kc * 32, eW0, kc * 32, 32, dcol);
        wait_grp(gslots, ep);
        stage_coh_T(XL, 644, 128, HT[cur], row0);
        __syncthreads();
        acc_segS(z, XL + b * 644 + 128 + kc * 128, eU0, kc * 128, 128, dcol);
        reduce4(z);
        float c1 = 0.f;
        if (lane < 16) {
            float h2 = lstm_fin(z, eb0, dcol, c_car, c1);
            st_coh(&HMT[(size_t)dcol * Bsz + bgl], h2);
        }
        arrive(&gslots[gm], ++ep);
        wait_grp(gslots, ep);
        stage_coh_T(XL, 516, 0, HMT, row0);
        __syncthreads();
        z = make_float4(0.f, 0.f, 0.f, 0.f);
        {
            const float4* wp = (const float4*)pWSUM + (size_t)dcol * 512 + kc * 128;
            const float* xp = XL + b * 516 + kc * 128;
            #pragma unroll 4
            for (int j = 0; j < 128; j += 4) {
                float4 x4 = *(const float4*)(xp + j);
                float4 w0 = wp[j], w1 = wp[j + 1], w2 = wp[j + 2], w3 = wp[j + 3];
                z.x += x4.x*w0.x + x4.y*w1.x + x4.z*w2.x + x4.w*w3.x;
                z.y += x4.x*w0.y + x4.y*w1.y + x4.z*w2.y + x4.w*w3.y;
                z.z += x4.x*w0.z + x4.y*w1.z + x4.z*w2.z + x4.w*w3.z;
                z.w += x4.x*w0.w + x4.y*w1.w + x4.z*w2.w + x4.w*w3.w;
            }
        }
        reduce4(z);
        if (lane < 16) {
            float c2;
            float h2 = lstm_fin(z, eb1, dcol, c1, c2);
            c_car = c2;
            st_coh(&HT[cur ^ 1][(size_t)dcol * Bsz + bgl], h2);
        }
        arrive(&gslots[gm], ++ep);
        cur ^= 1;
    }

    stage_vec(XL, 644, 0, dec_in, row0, Tsz * Fsz, 128, 5);
    __syncthreads();
    {
        float4 z = make_float4(0.f, 0.f, 0.f, 0.f);
        acc_segS(z, XL + b * 644 + kc * 32, dW0, kc * 32, 32, dcol);
        wait_grp(gslots, ep);
        stage_coh_T(XL, 644, 128, HT[cur], row0);
        __syncthreads();
        acc_segS(z, XL + b * 644 + 128 + kc * 128, dU0, kc * 128, 128, dcol);
        reduce4(z);
        if (lane < 16) {
            float cd;
            float h2 = lstm_fin(z, db0, dcol, c_car, cd);
            st_coh(&HMT[(size_t)dcol * Bsz + bgl], h2);
        }
        arrive(&gslots[gm], ++ep);
    }
    wait_grp(gslots, ep);
    stage_coh_T(XL, 1028, 0, HT[cur], row0);
    stage_coh_T(XL, 1028, 512, HMT, row0);
    __syncthreads();
    {
        float4 z = make_float4(0.f, 0.f, 0.f, 0.f);
        acc_segS(z, XL + b * 1028 + kc * 128, dU1, kc * 128, 128, dcol);
        acc_segS(z, XL + b * 1028 + 512 + kc * 128, dW1, kc * 128, 128, dcol);
        reduce4(z);
        if (lane < 16) {
            float c2;
            float h2 = lstm_fin(z, db1, dcol, c_car, c2);
            c_car = c2;
            st_coh(&HT[cur ^ 1][(size_t)dcol * Bsz + bgl], h2);
        }
    }
    arrive(&gslots[gm], ++ep);
    cur ^= 1;

    for (int t = 1; t < Tsz; ++t) {
        const int tt = Tsz - t;
        wait_grp(gslots, ep);
        stage_coh_T(XL, 1028, 0, HT[cur], row0);
        __syncthreads();
        {
            float4 z = make_float4(0.f, 0.f, 0.f, 0.f);
            const float4* wp = (const float4*)pWDECA + (size_t)dcol * 512 + kc * 128;
            const float* xp = XL + b * 1028 + kc * 128;
            #pragma unroll 4
            for (int j = 0; j < 128; j += 4) {
                float4 x4 = *(const float4*)(xp + j);
                float4 w0 = wp[j], w1 = wp[j + 1], w2 = wp[j + 2], w3 = wp[j + 3];
                z.x += x4.x*w0.x + x4.y*w1.x + x4.z*w2.x + x4.w*w3.x;
                z.y += x4.x*w0.y + x4.y*w1.y + x4.z*w2.y + x4.w*w3.y;
                z.z += x4.x*w0.z + x4.y*w1.z + x4.z*w2.z + x4.w*w3.z;
                z.w += x4.x*w0.w + x4.y*w1.w + x4.z*w2.w + x4.w*w3.w;
            }
            reduce4(z);
            out_part(XL, 1028, ORED, b, kc, w, fcol, pDWT);
            if (lane < 16) {
                float cd;
                float h2 = lstm_fin(z, pBF, dcol, c_car, cd);
                st_coh(&HMT[(size_t)dcol * Bsz + bgl], h2);
            }
        }
        arrive(&gslots[gm], ++ep);
        if (tid < 64) {
            const int bb = tid >> 2, ff = tid & 3;
            const int fc = grp * 16 + dslc * 4 + ff;
            const float* r = ORED + bb * 16 + ff * 4;
            float s = r[0] + r[1] + r[2] + r[3] + db_[fc];
            out[((size_t)(row0 + bb) * Tsz + tt) * Fsz + fc] = s;
        }
        wait_grp(gslots, ep);
        stage_coh_T(XL, 1028, 512, HMT, row0);
        __syncthreads();
        {
            float4 z = make_float4(0.f, 0.f, 0.f, 0.f);
            acc_segS(z, XL + b * 1028 + kc * 128, dU1, kc * 128, 128, dcol);
            acc_segS(z, XL + b * 1028 + 512 + kc * 128, dW1, kc * 128, 128, dcol);
            reduce4(z);
            if (lane < 16) {
                float c2;
                float h2 = lstm_fin(z, db1, dcol, c_car, c2);
                c_car = c2;
                st_coh(&HT[cur ^ 1][(size_t)dcol * Bsz + bgl], h2);
            }
        }
        arrive(&gslots[gm], ++ep);
        cur ^= 1;
    }

    wait_grp(gslots, ep);
    stage_coh_T(XL, 516, 0, HT[cur], row0);
    __syncthreads();
    out_part(XL, 516, ORED, b, kc, w, fcol, pDWT);
    __syncthreads();
    if (tid < 64) {
        const int bb = tid >> 2, ff = tid & 3;
        const int fc = grp * 16 + dslc * 4 + ff;
        const float* r = ORED + bb * 16 + ff * 4;
        float s = r[0] + r[1] + r[2] + r[3] + db_[fc];
        out[((size_t)(row0 + bb) * Tsz + 0) * Fsz + fc] = s;
    }
}

extern "C" void kernel_launch(void* const* d_in, const int* in_sizes, int n_in,
                              void* d_out, int out_size, void* d_ws, size_t ws_size,
                              hipStream_t stream) {
    (void)in_sizes; (void)n_in; (void)out_size;
    const float* enc_in = (const float*)d_in[0];
    const float* dec_in = (const float*)d_in[1];
    const float* eW0 = (const float*)d_in[2];
    const float* eU0 = (const float*)d_in[3];
    const float* eb0 = (const float*)d_in[4];
    const float* eW1 = (const float*)d_in[5];
    const float* eU1 = (const float*)d_in[6];
    const float* eb1 = (const float*)d_in[7];
    const float* dW0 = (const float*)d_in[8];
    const float* dU0 = (const float*)d_in[9];
    const float* db0 = (const float*)d_in[10];
    const float* dW1 = (const float*)d_in[11];
    const float* dU1 = (const float*)d_in[12];
    const float* db1 = (const float*)d_in[13];
    const float* dw  = (const float*)d_in[14];
    const float* db_ = (const float*)d_in[15];
    float* out = (float*)d_out;
    float* ws = (float*)d_ws;

    // zero: full-grid slots + 16x32 chain slots + HT0 (initial h = 0)
    hipMemsetAsync(d_ws, 0, (size_t)(OFF_HT0 + Dsz * Bsz) * sizeof(float), stream);

    if (ws_size >= (size_t)WS_PACKED_FLOATS * sizeof(float))
        lstm_ae_v10<<<NBLK, NTHR, 0, stream>>>(
            enc_in, dec_in, eW0, eU0, eb0, eW1, eU1, eb1,
            dW0, dU0, db0, dW1, dU1, db1, dw, db_, out, ws);
    else
        lstm_ae_fb<<<NBLK, NTHR, 0, stream>>>(
            enc_in, dec_in, eW0, eU0, eb0, eW1, eU1, eb1,
            dW0, dU0, db0, dW1, dU1, db1, dw, db_, out, ws);
}